// Round 1
// baseline (920.156 us; speedup 1.0000x reference)
//
#include <hip/hip_runtime.h>
#include <hip/hip_bf16.h>
#include <math.h>

#define N_ 4
#define C_ 1024
#define D_ 768
#define H_ 12
#define E_ 32
#define M_ 4
#define P_ 256
#define NL_ 97
#define NP_ (N_*P_)
#define K3D_ 2304

__device__ __forceinline__ float blockReduceSum256(float v){
  __shared__ float red_s[4];
  #pragma unroll
  for (int o=32;o>0;o>>=1) v += __shfl_down(v, o);
  if ((threadIdx.x & 63)==0) red_s[threadIdx.x>>6] = v;
  __syncthreads();
  float t = red_s[0]+red_s[1]+red_s[2]+red_s[3];
  __syncthreads();
  return t;
}

// K1: ent_emb[n,e,:] = logsumexp_m seq[n, pos[n,e,m], :]
__global__ __launch_bounds__(256) void k_ent_emb(const float* __restrict__ seq,
    const int* __restrict__ pos, float* __restrict__ ent_emb){
  const int be = blockIdx.x;           // n*E+e
  const int n = be >> 5;
  const int* pp = pos + be*M_;
  const float* s0 = seq + ((size_t)n*C_ + pp[0])*D_;
  const float* s1 = seq + ((size_t)n*C_ + pp[1])*D_;
  const float* s2 = seq + ((size_t)n*C_ + pp[2])*D_;
  const float* s3 = seq + ((size_t)n*C_ + pp[3])*D_;
  for (int d=threadIdx.x; d<D_; d+=256){
    float v0=s0[d], v1=s1[d], v2=s2[d], v3=s3[d];
    float m = fmaxf(fmaxf(v0,v1), fmaxf(v2,v3));
    float s = expf(v0-m)+expf(v1-m)+expf(v2-m)+expf(v3-m);
    ent_emb[(size_t)be*D_ + d] = m + logf(s);
  }
}

// K2: ent_att[n,e,h,c] = mean_m attn[n,h,pos[n,e,m],c]
__global__ __launch_bounds__(256) void k_ent_att(const float* __restrict__ attn,
    const int* __restrict__ pos, float* __restrict__ ent_att){
  const int b = blockIdx.x;            // (n*E+e)*H + h
  const int h = b % H_;
  const int ne = b / H_;
  const int n = ne >> 5;
  const int* pp = pos + ne*M_;
  const float* base = attn + ((size_t)(n*H_+h))*C_*C_;
  const float* r0 = base + (size_t)pp[0]*C_;
  const float* r1 = base + (size_t)pp[1]*C_;
  const float* r2 = base + (size_t)pp[2]*C_;
  const float* r3 = base + (size_t)pp[3]*C_;
  float* outp = ent_att + (size_t)b*C_;
  for (int c=threadIdx.x; c<C_; c+=256)
    outp[c] = 0.25f*(r0[c]+r1[c]+r2[c]+r3[c]);
}

// K3: ht_att[n,p,c] = normalized mean_h ea[n,he,h,c]*ea[n,te,h,c]
__global__ __launch_bounds__(256) void k_ht_att(const float* __restrict__ ent_att,
    const int* __restrict__ hts, float* __restrict__ ht_att){
  const int r = blockIdx.x;            // n*P+p
  const int n = r >> 8;
  const int he = hts[r*2], te = hts[r*2+1];
  const float* ha = ent_att + ((size_t)(n*E_+he))*H_*C_;
  const float* ta = ent_att + ((size_t)(n*E_+te))*H_*C_;
  float vals[4]; float local = 0.f;
  #pragma unroll
  for (int u=0;u<4;u++){
    const int c = threadIdx.x + u*256;
    float acc = 0.f;
    #pragma unroll
    for (int h=0;h<H_;h++) acc = fmaf(ha[h*C_+c], ta[h*C_+c], acc);
    vals[u] = acc * (1.0f/H_);
    local += vals[u];
  }
  const float tot = blockReduceSum256(local);
  const float den = tot + 1e-5f;
  #pragma unroll
  for (int u=0;u<4;u++)
    ht_att[(size_t)r*C_ + threadIdx.x + u*256] = vals[u]/den;
}

// K4: rs[n] = ht_att[n] (256x1024) @ seq[n] (1024x768)
__global__ __launch_bounds__(256) void k_gemm_rs(const float* __restrict__ htA,
    const float* __restrict__ seq, float* __restrict__ rs){
  constexpr int BM=64, BN=64, BK=16, TM=4, TN=4;
  const int n = blockIdx.z;
  const float* A = htA + (size_t)n*P_*C_;
  const float* B = seq + (size_t)n*C_*D_;
  float* Cm = rs + (size_t)n*P_*D_;
  const int bm = blockIdx.y*BM, bn = blockIdx.x*BN;
  __shared__ float As[BK][BM+1];
  __shared__ float Bs[BK][BN];
  const int tx = threadIdx.x & 15, ty = threadIdx.x >> 4;
  float acc[TM][TN] = {};
  for (int k0=0;k0<C_;k0+=BK){
    for (int x=threadIdx.x; x<BM*BK; x+=256){
      int row = x>>4, kk = x&15;
      As[kk][row] = A[(size_t)(bm+row)*C_ + k0+kk];
    }
    for (int x=threadIdx.x; x<BK*BN; x+=256){
      int kk = x>>6, col = x&63;
      Bs[kk][col] = B[(size_t)(k0+kk)*D_ + bn+col];
    }
    __syncthreads();
    #pragma unroll
    for (int kk=0;kk<BK;kk++){
      float a[TM], bfr[TN];
      #pragma unroll
      for (int i=0;i<TM;i++) a[i] = As[kk][ty*TM+i];
      #pragma unroll
      for (int j=0;j<TN;j++) bfr[j] = Bs[kk][tx*TN+j];
      #pragma unroll
      for (int i=0;i<TM;i++)
        #pragma unroll
        for (int j=0;j<TN;j++)
          acc[i][j] = fmaf(a[i], bfr[j], acc[i][j]);
    }
    __syncthreads();
  }
  #pragma unroll
  for (int i=0;i<TM;i++)
    #pragma unroll
    for (int j=0;j<TN;j++)
      Cm[(size_t)(bm+ty*TM+i)*D_ + bn+tx*TN+j] = acc[i][j];
}

// K5: KK[r,:] = seq[n, pos[r], :] @ Wk + bk   (r over N*E*M = 512 rows)
__global__ __launch_bounds__(256) void k_KK(const float* __restrict__ seq,
    const int* __restrict__ pos, const float* __restrict__ Wk,
    const float* __restrict__ bk, float* __restrict__ KK){
  const int r0 = blockIdx.x*4;
  __shared__ float xs[4][D_];
  #pragma unroll
  for (int q=0;q<4;q++){
    const int r = r0+q;
    const int n = r >> 7;            // /(E_*M_)=128
    const int c = pos[r];
    const float* src = seq + ((size_t)n*C_ + c)*D_;
    for (int d=threadIdx.x; d<D_; d+=256) xs[q][d] = src[d];
  }
  __syncthreads();
  const int d0 = threadIdx.x;
  float acc[4][3];
  #pragma unroll
  for (int q=0;q<4;q++){
    acc[q][0] = bk[d0]; acc[q][1] = bk[d0+256]; acc[q][2] = bk[d0+512];
  }
  for (int k=0;k<D_;k++){
    const float w0 = Wk[(size_t)k*D_ + d0];
    const float w1 = Wk[(size_t)k*D_ + d0+256];
    const float w2 = Wk[(size_t)k*D_ + d0+512];
    #pragma unroll
    for (int q=0;q<4;q++){
      const float a = xs[q][k];
      acc[q][0] = fmaf(a,w0,acc[q][0]);
      acc[q][1] = fmaf(a,w1,acc[q][1]);
      acc[q][2] = fmaf(a,w2,acc[q][2]);
    }
  }
  #pragma unroll
  for (int q=0;q<4;q++){
    KK[(size_t)(r0+q)*D_ + d0]     = acc[q][0];
    KK[(size_t)(r0+q)*D_ + d0+256] = acc[q][1];
    KK[(size_t)(r0+q)*D_ + d0+512] = acc[q][2];
  }
}

// K6: kdot[512], vq[768] = Wq@aw_top rowdots, qc = bq.aw_top + ab
__global__ __launch_bounds__(256) void k_smalldots(const float* __restrict__ KK,
    const float* __restrict__ aw, const float* __restrict__ ab,
    const float* __restrict__ Wq, const float* __restrict__ bq,
    float* __restrict__ kdot, float* __restrict__ vq, float* __restrict__ qc){
  const int b = blockIdx.x;
  float s = 0.f;
  if (b < N_*E_*M_){
    const float* row = KK + (size_t)b*D_;
    for (int d=threadIdx.x; d<D_; d+=256) s += row[d]*aw[D_+d];
    s = blockReduceSum256(s);
    if (threadIdx.x==0) kdot[b] = s;
  } else if (b < N_*E_*M_ + D_){
    const int k = b - N_*E_*M_;
    const float* row = Wq + (size_t)k*D_;
    for (int d=threadIdx.x; d<D_; d+=256) s += row[d]*aw[d];
    s = blockReduceSum256(s);
    if (threadIdx.x==0) vq[k] = s;
  } else {
    for (int d=threadIdx.x; d<D_; d+=256) s += bq[d]*aw[d];
    s = blockReduceSum256(s);
    if (threadIdx.x==0) qc[0] = s + ab[0];
  }
}

// K7: qdot[r] = rs[r].vq + qc
__global__ __launch_bounds__(256) void k_qdot(const float* __restrict__ rs,
    const float* __restrict__ vq, const float* __restrict__ qc, float* __restrict__ qdot){
  const int r = blockIdx.x;
  float s = 0.f;
  for (int d=threadIdx.x; d<D_; d+=256) s += rs[(size_t)r*D_+d]*vq[d];
  s = blockReduceSum256(s);
  if (threadIdx.x==0) qdot[r] = s + qc[0];
}

// K8: hess/tess[r,:] = softmax(leaky(qdot+kdot) masked) . KK rows
__global__ __launch_bounds__(256) void k_mention(const float* __restrict__ KK,
    const float* __restrict__ kdot, const float* __restrict__ qdot,
    const int* __restrict__ pos, const int* __restrict__ hts,
    float* __restrict__ hess, float* __restrict__ tess){
  const int b = blockIdx.x;       // r*2+side
  const int side = b & 1;
  const int r = b >> 1;
  const int n = r >> 8;
  const int e = hts[r*2 + side];
  const int base = (n*E_ + e)*M_;
  const float q = qdot[r];
  float sc[M_];
  #pragma unroll
  for (int m=0;m<M_;m++){
    float s = q + kdot[base+m];
    s = (s > 0.f) ? s : 0.01f*s;
    sc[m] = (pos[base+m] != 0) ? s : -1e9f;
  }
  const float mx = fmaxf(fmaxf(sc[0],sc[1]), fmaxf(sc[2],sc[3]));
  float ex[M_]; float sum=0.f;
  #pragma unroll
  for (int m=0;m<M_;m++){ ex[m] = expf(sc[m]-mx); sum += ex[m]; }
  const float inv = 1.f/sum;
  float* outp = (side ? tess : hess) + (size_t)r*D_;
  const float* K0 = KK + (size_t)(base+0)*D_;
  const float* K1 = KK + (size_t)(base+1)*D_;
  const float* K2 = KK + (size_t)(base+2)*D_;
  const float* K3 = KK + (size_t)(base+3)*D_;
  const float p0=ex[0]*inv, p1=ex[1]*inv, p2=ex[2]*inv, p3=ex[3]*inv;
  for (int d=threadIdx.x; d<D_; d+=256)
    outp[d] = p0*K0[d] + p1*K1[d] + p2*K2[d] + p3*K3[d];
}

// K9: zh/zt = act( [rs|hs|hess] @ W + b ); A-concat fused into tile loader
__global__ __launch_bounds__(256) void k_gemm_z(
    const float* __restrict__ rs, const float* __restrict__ ent_emb,
    const float* __restrict__ hess, const float* __restrict__ tess,
    const int* __restrict__ hts,
    const float* __restrict__ Wh, const float* __restrict__ Wt,
    const float* __restrict__ bh, const float* __restrict__ bt,
    float* __restrict__ zh, float* __restrict__ zt){
  constexpr int BM=64, BN=64, BK=16, TM=4, TN=4;
  const int side = blockIdx.z;
  const float* B    = side ? Wt : Wh;
  const float* bias = side ? bt : bh;
  const float* hx   = side ? tess : hess;
  float* Cm = side ? zt : zh;
  const int bm = blockIdx.y*BM, bn = blockIdx.x*BN;
  __shared__ float As[BK][BM+1];
  __shared__ float Bs[BK][BN];
  __shared__ int e_s[BM];
  if (threadIdx.x < BM) e_s[threadIdx.x] = hts[(bm+threadIdx.x)*2 + side];
  __syncthreads();
  const int tx = threadIdx.x & 15, ty = threadIdx.x >> 4;
  float acc[TM][TN] = {};
  for (int k0=0;k0<K3D_;k0+=BK){
    for (int x=threadIdx.x; x<BM*BK; x+=256){
      int row = x>>4, kk = x&15;
      int rr = bm+row, gk = k0+kk;
      float v;
      if (gk < D_)        v = rs[(size_t)rr*D_ + gk];
      else if (gk < 2*D_) v = ent_emb[(size_t)((rr>>8)*E_ + e_s[row])*D_ + (gk-D_)];
      else                v = hx[(size_t)rr*D_ + (gk-2*D_)];
      As[kk][row] = v;
    }
    for (int x=threadIdx.x; x<BK*BN; x+=256){
      int kk = x>>6, col = x&63;
      Bs[kk][col] = B[(size_t)(k0+kk)*D_ + bn+col];
    }
    __syncthreads();
    #pragma unroll
    for (int kk=0;kk<BK;kk++){
      float a[TM], bfr[TN];
      #pragma unroll
      for (int i=0;i<TM;i++) a[i] = As[kk][ty*TM+i];
      #pragma unroll
      for (int j=0;j<TN;j++) bfr[j] = Bs[kk][tx*TN+j];
      #pragma unroll
      for (int i=0;i<TM;i++)
        #pragma unroll
        for (int j=0;j<TN;j++)
          acc[i][j] = fmaf(a[i], bfr[j], acc[i][j]);
    }
    __syncthreads();
  }
  #pragma unroll
  for (int i=0;i<TM;i++)
    #pragma unroll
    for (int j=0;j<TN;j++){
      float v = acc[i][j] + bias[bn+tx*TN+j];
      v = tanhf(v);
      if (side==0) v = tanhf(v);
      Cm[(size_t)(bm+ty*TM+i)*D_ + bn+tx*TN+j] = v;
    }
}

// K10: partial[kc][r][l] = sum over this kchunk of bl[r,k]*Wb[k,l],
//      bl generated on the fly from zh x zt outer products
__global__ __launch_bounds__(256) void k_bilinear(const float* __restrict__ zh,
    const float* __restrict__ zt, const float* __restrict__ Wb, float* __restrict__ partial){
  const int kc = blockIdx.x;        // 0..23 : blk = kc>>1, i-half = kc&1
  const int blk = kc >> 1;
  const int i0 = (kc & 1)*32;
  const int r0 = blockIdx.y*64;
  __shared__ float zh_s[64][33];
  __shared__ float zt_s[64][65];
  __shared__ float Bsf[64*NL_];
  const int tid = threadIdx.x;
  for (int x=tid; x<64*32; x+=256){
    int row = x>>5, ii = x&31;
    zh_s[row][ii] = zh[(size_t)(r0+row)*D_ + blk*64 + i0 + ii];
  }
  for (int x=tid; x<64*64; x+=256){
    int row = x>>6, j = x&63;
    zt_s[row][j] = zt[(size_t)(r0+row)*D_ + blk*64 + j];
  }
  const int tx = tid & 15, ty = tid >> 4;
  float acc[4][7] = {};
  for (int ii=0; ii<32; ii++){
    __syncthreads();
    const float* wsrc = Wb + (size_t)(blk*4096 + (i0+ii)*64)*NL_;
    for (int x=tid; x<64*NL_; x+=256) Bsf[x] = wsrc[x];
    __syncthreads();
    float ah[4];
    #pragma unroll
    for (int q=0;q<4;q++) ah[q] = zh_s[ty*4+q][ii];
    for (int j=0;j<64;j++){
      float av[4];
      #pragma unroll
      for (int q=0;q<4;q++) av[q] = ah[q]*zt_s[ty*4+q][j];
      float bv[7];
      #pragma unroll
      for (int c=0;c<6;c++) bv[c] = Bsf[j*NL_ + tx + 16*c];
      bv[6] = (tx==0) ? Bsf[j*NL_ + 96] : 0.f;
      #pragma unroll
      for (int q=0;q<4;q++)
        #pragma unroll
        for (int c=0;c<7;c++)
          acc[q][c] = fmaf(av[q], bv[c], acc[q][c]);
    }
  }
  #pragma unroll
  for (int q=0;q<4;q++){
    const int r = r0 + ty*4 + q;
    #pragma unroll
    for (int c=0;c<7;c++){
      const int l = tx + 16*c;
      if (l < NL_)
        partial[((size_t)kc*NP_ + r)*NL_ + l] = acc[q][c];
    }
  }
}

// K11: out = sum partials + bb
__global__ __launch_bounds__(256) void k_reduce(const float* __restrict__ partial,
    const float* __restrict__ bb, float* __restrict__ out){
  const int idx = blockIdx.x*256 + threadIdx.x;
  if (idx >= NP_*NL_) return;
  const int l = idx % NL_;
  float s = bb[l];
  #pragma unroll
  for (int kc=0;kc<24;kc++) s += partial[(size_t)kc*NP_*NL_ + idx];
  out[idx] = s;
}

extern "C" void kernel_launch(void* const* d_in, const int* in_sizes, int n_in,
                              void* d_out, int out_size, void* d_ws, size_t ws_size,
                              hipStream_t stream){
  const float* seq  = (const float*)d_in[0];
  const float* attn = (const float*)d_in[1];
  const int*   pos  = (const int*)d_in[2];
  const int*   hts  = (const int*)d_in[3];
  const float* Wq = (const float*)d_in[4];
  const float* bq = (const float*)d_in[5];
  const float* Wk = (const float*)d_in[6];
  const float* bk = (const float*)d_in[7];
  const float* aw = (const float*)d_in[8];
  const float* ab = (const float*)d_in[9];
  const float* Wh = (const float*)d_in[10];
  const float* bh = (const float*)d_in[11];
  const float* Wt = (const float*)d_in[12];
  const float* bt = (const float*)d_in[13];
  const float* Wb = (const float*)d_in[14];
  const float* bb = (const float*)d_in[15];
  float* out = (float*)d_out;
  float* w = (float*)d_ws;
  size_t o = 0;
  float* ent_emb = w+o; o += (size_t)N_*E_*D_;
  float* ent_att = w+o; o += (size_t)N_*E_*H_*C_;
  float* ht_att  = w+o; o += (size_t)N_*P_*C_;
  float* rs      = w+o; o += (size_t)NP_*D_;
  float* KK      = w+o; o += (size_t)N_*E_*M_*D_;
  float* kdot    = w+o; o += N_*E_*M_;
  float* vq      = w+o; o += D_;
  float* qc      = w+o; o += 1;
  float* qdot    = w+o; o += NP_;
  float* hess    = w+o; o += (size_t)NP_*D_;
  float* tess    = w+o; o += (size_t)NP_*D_;
  float* zh      = w+o; o += (size_t)NP_*D_;
  float* zt      = w+o; o += (size_t)NP_*D_;
  float* partial = w+o; o += (size_t)24*NP_*NL_;
  (void)ws_size; (void)in_sizes; (void)n_in; (void)out_size;

  k_ent_emb<<<N_*E_, 256, 0, stream>>>(seq, pos, ent_emb);
  k_ent_att<<<N_*E_*H_, 256, 0, stream>>>(attn, pos, ent_att);
  k_ht_att<<<NP_, 256, 0, stream>>>(ent_att, hts, ht_att);
  k_gemm_rs<<<dim3(D_/64, P_/64, N_), 256, 0, stream>>>(ht_att, seq, rs);
  k_KK<<<(N_*E_*M_)/4, 256, 0, stream>>>(seq, pos, Wk, bk, KK);
  k_smalldots<<<N_*E_*M_ + D_ + 1, 256, 0, stream>>>(KK, aw, ab, Wq, bq, kdot, vq, qc);
  k_qdot<<<NP_, 256, 0, stream>>>(rs, vq, qc, qdot);
  k_mention<<<NP_*2, 256, 0, stream>>>(KK, kdot, qdot, pos, hts, hess, tess);
  k_gemm_z<<<dim3(D_/64, NP_/64, 2), 256, 0, stream>>>(rs, ent_emb, hess, tess, hts,
                                                       Wh, Wt, bh, bt, zh, zt);
  k_bilinear<<<dim3(24, NP_/64), 256, 0, stream>>>(zh, zt, Wb, partial);
  k_reduce<<<(NP_*NL_+255)/256, 256, 0, stream>>>(partial, bb, out);
}

// Round 2
// 178.438 us; speedup vs baseline: 5.1567x; 5.1567x over previous
//
#include <hip/hip_runtime.h>
#include <hip/hip_bf16.h>
#include <math.h>

#define N_ 4
#define C_ 1024
#define D_ 768
#define H_ 12
#define E_ 32
#define M_ 4
#define P_ 256
#define NL_ 97
#define NLP_ 112
#define NP_ (N_*P_)
#define K3D_ 2304
#define KBL_ 49152

typedef __attribute__((ext_vector_type(8))) short short8;
typedef __attribute__((ext_vector_type(4))) float f32x4;

__device__ __forceinline__ short f2bf(float x){
  union { __hip_bfloat16 h; short s; } u; u.h = __float2bfloat16(x); return u.s;
}

__device__ __forceinline__ float blockReduceSum256(float v){
  __shared__ float red_s[4];
  #pragma unroll
  for (int o=32;o>0;o>>=1) v += __shfl_down(v, o);
  if ((threadIdx.x & 63)==0) red_s[threadIdx.x>>6] = v;
  __syncthreads();
  float t = red_s[0]+red_s[1]+red_s[2]+red_s[3];
  __syncthreads();
  return t;
}

// ---- transpose + fp32->bf16: in [R][C] f32 -> out [Cp][R] bf16 (zero-pad cols >= C)
__global__ __launch_bounds__(256) void k_tcvt(const float* __restrict__ in,
    __hip_bfloat16* __restrict__ out, int R, int C, int Cp){
  __shared__ float t[32][33];
  const int rb = blockIdx.x*32, cb = blockIdx.y*32;
  const int tx = threadIdx.x & 31, ty = threadIdx.x >> 5;   // ty 0..7
  #pragma unroll
  for (int i=0;i<4;i++){
    const int r = ty + i*8;
    const int c = cb + tx;
    t[r][tx] = (c < C) ? in[(size_t)(rb+r)*C + c] : 0.f;
  }
  __syncthreads();
  #pragma unroll
  for (int i=0;i<4;i++){
    const int cr = ty + i*8;          // local out-row (C dim)
    const int cc = cb + cr;
    if (cc < Cp)
      out[(size_t)cc*R + rb + tx] = __float2bfloat16(t[tx][cr]);
  }
}

// K1: ent_emb_bf[n,e,:] = bf16( logsumexp_m seq[n, pos[n,e,m], :] )
__global__ __launch_bounds__(256) void k_ent_emb(const float* __restrict__ seq,
    const int* __restrict__ pos, __hip_bfloat16* __restrict__ ent_bf){
  const int be = blockIdx.x;
  const int n = be >> 5;
  const int* pp = pos + be*M_;
  const float* s0 = seq + ((size_t)n*C_ + pp[0])*D_;
  const float* s1 = seq + ((size_t)n*C_ + pp[1])*D_;
  const float* s2 = seq + ((size_t)n*C_ + pp[2])*D_;
  const float* s3 = seq + ((size_t)n*C_ + pp[3])*D_;
  for (int d=threadIdx.x; d<D_; d+=256){
    float v0=s0[d], v1=s1[d], v2=s2[d], v3=s3[d];
    float m = fmaxf(fmaxf(v0,v1), fmaxf(v2,v3));
    float s = expf(v0-m)+expf(v1-m)+expf(v2-m)+expf(v3-m);
    ent_bf[(size_t)be*D_ + d] = __float2bfloat16(m + logf(s));
  }
}

// K2: ent_att[n,e,h,c] = mean_m attn[n,h,pos[n,e,m],c]
__global__ __launch_bounds__(256) void k_ent_att(const float* __restrict__ attn,
    const int* __restrict__ pos, float* __restrict__ ent_att){
  const int b = blockIdx.x;
  const int h = b % H_;
  const int ne = b / H_;
  const int n = ne >> 5;
  const int* pp = pos + ne*M_;
  const float* base = attn + ((size_t)(n*H_+h))*C_*C_;
  const float* r0 = base + (size_t)pp[0]*C_;
  const float* r1 = base + (size_t)pp[1]*C_;
  const float* r2 = base + (size_t)pp[2]*C_;
  const float* r3 = base + (size_t)pp[3]*C_;
  float* outp = ent_att + (size_t)b*C_;
  for (int c=threadIdx.x; c<C_; c+=256)
    outp[c] = 0.25f*(r0[c]+r1[c]+r2[c]+r3[c]);
}

// K3: ht_att_bf[n,p,c] (bf16) = normalized mean_h ea[he]*ea[te]
__global__ __launch_bounds__(256) void k_ht_att(const float* __restrict__ ent_att,
    const int* __restrict__ hts, __hip_bfloat16* __restrict__ ht_bf){
  const int r = blockIdx.x;
  const int n = r >> 8;
  const int he = hts[r*2], te = hts[r*2+1];
  const float* ha = ent_att + ((size_t)(n*E_+he))*H_*C_;
  const float* ta = ent_att + ((size_t)(n*E_+te))*H_*C_;
  float vals[4]; float local = 0.f;
  #pragma unroll
  for (int u=0;u<4;u++){
    const int c = threadIdx.x + u*256;
    float acc = 0.f;
    #pragma unroll
    for (int h=0;h<H_;h++) acc = fmaf(ha[h*C_+c], ta[h*C_+c], acc);
    vals[u] = acc * (1.0f/H_);
    local += vals[u];
  }
  const float tot = blockReduceSum256(local);
  const float den = tot + 1e-5f;
  #pragma unroll
  for (int u=0;u<4;u++)
    ht_bf[(size_t)r*C_ + threadIdx.x + u*256] = __float2bfloat16(vals[u]/den);
}

// gather mention rows of seq as bf16: Abf[r][d] = bf16(seq[n, pos[r], d])
__global__ __launch_bounds__(256) void k_gatherA(const float* __restrict__ seq,
    const int* __restrict__ pos, __hip_bfloat16* __restrict__ Abf){
  const int r = blockIdx.x;
  const int n = r >> 7;
  const int c = pos[r];
  const float* src = seq + ((size_t)n*C_ + c)*D_;
  for (int d=threadIdx.x; d<D_; d+=256)
    Abf[(size_t)r*D_ + d] = __float2bfloat16(src[d]);
}

// MFMA GEMM: KK[512][768] = Abf @ Wk + bk  (WkT [768][768] bf16)
__global__ __launch_bounds__(256) void k_KKg(const __hip_bfloat16* __restrict__ Abf,
    const __hip_bfloat16* __restrict__ WkT, const float* __restrict__ bk,
    float* __restrict__ KK){
  const int bm = blockIdx.y*64, bn = blockIdx.x*64;
  __shared__ short As[64][40];
  __shared__ short Bs[64][40];
  const int tid = threadIdx.x;
  const int w = tid>>6, l = tid&63;
  const int wm = w>>1, wn = w&1;
  const int lrow = tid>>2, lk8 = (tid&3)*8;
  const short* Ap = (const short*)Abf;
  const short* Bp = (const short*)WkT;
  f32x4 acc[2][2] = {};
  for (int k0=0;k0<D_;k0+=32){
    *(short8*)&As[lrow][lk8] = *(const short8*)&Ap[(size_t)(bm+lrow)*D_ + k0 + lk8];
    *(short8*)&Bs[lrow][lk8] = *(const short8*)&Bp[(size_t)(bn+lrow)*D_ + k0 + lk8];
    __syncthreads();
    short8 af[2], bfv[2];
    #pragma unroll
    for (int f=0;f<2;f++){
      af[f]  = *(short8*)&As[wm*32+f*16+(l&15)][(l>>4)*8];
      bfv[f] = *(short8*)&Bs[wn*32+f*16+(l&15)][(l>>4)*8];
    }
    #pragma unroll
    for (int i=0;i<2;i++)
      #pragma unroll
      for (int j=0;j<2;j++)
        acc[i][j] = __builtin_amdgcn_mfma_f32_16x16x32_bf16(af[i], bfv[j], acc[i][j], 0,0,0);
    __syncthreads();
  }
  #pragma unroll
  for (int i=0;i<2;i++)
    #pragma unroll
    for (int j=0;j<2;j++)
      #pragma unroll
      for (int r=0;r<4;r++){
        const int row = bm + wm*32 + i*16 + (l>>4)*4 + r;
        const int col = bn + wn*32 + j*16 + (l&15);
        KK[(size_t)row*D_ + col] = acc[i][j][r] + bk[col];
      }
}

// MFMA GEMM: rs[n] = ht_att[n] @ seq[n]; writes rs (f32) and rs_bf
__global__ __launch_bounds__(256) void k_gemm_rs(const __hip_bfloat16* __restrict__ htA,
    const __hip_bfloat16* __restrict__ seqT, float* __restrict__ rs,
    __hip_bfloat16* __restrict__ rs_bf){
  const int n = blockIdx.z;
  const int bm = blockIdx.y*64, bn = blockIdx.x*64;
  __shared__ short As[64][40];
  __shared__ short Bs[64][40];
  const int tid = threadIdx.x;
  const int w = tid>>6, l = tid&63;
  const int wm = w>>1, wn = w&1;
  const int lrow = tid>>2, lk8 = (tid&3)*8;
  const short* Ap = (const short*)htA + (size_t)n*P_*C_;
  const short* Bp = (const short*)seqT;
  f32x4 acc[2][2] = {};
  for (int k0=0;k0<C_;k0+=32){
    *(short8*)&As[lrow][lk8] = *(const short8*)&Ap[(size_t)(bm+lrow)*C_ + k0 + lk8];
    *(short8*)&Bs[lrow][lk8] = *(const short8*)&Bp[(size_t)(bn+lrow)*(N_*C_) + n*C_ + k0 + lk8];
    __syncthreads();
    short8 af[2], bfv[2];
    #pragma unroll
    for (int f=0;f<2;f++){
      af[f]  = *(short8*)&As[wm*32+f*16+(l&15)][(l>>4)*8];
      bfv[f] = *(short8*)&Bs[wn*32+f*16+(l&15)][(l>>4)*8];
    }
    #pragma unroll
    for (int i=0;i<2;i++)
      #pragma unroll
      for (int j=0;j<2;j++)
        acc[i][j] = __builtin_amdgcn_mfma_f32_16x16x32_bf16(af[i], bfv[j], acc[i][j], 0,0,0);
    __syncthreads();
  }
  #pragma unroll
  for (int i=0;i<2;i++)
    #pragma unroll
    for (int j=0;j<2;j++)
      #pragma unroll
      for (int r=0;r<4;r++){
        const int row = bm + wm*32 + i*16 + (l>>4)*4 + r;
        const int col = bn + wn*32 + j*16 + (l&15);
        const float v = acc[i][j][r];
        const size_t idx = ((size_t)n*P_ + row)*D_ + col;
        rs[idx] = v;
        rs_bf[idx] = __float2bfloat16(v);
      }
}

// K6: kdot[512], vq[768], qc
__global__ __launch_bounds__(256) void k_smalldots(const float* __restrict__ KK,
    const float* __restrict__ aw, const float* __restrict__ ab,
    const float* __restrict__ Wq, const float* __restrict__ bq,
    float* __restrict__ kdot, float* __restrict__ vq, float* __restrict__ qc){
  const int b = blockIdx.x;
  float s = 0.f;
  if (b < N_*E_*M_){
    const float* row = KK + (size_t)b*D_;
    for (int d=threadIdx.x; d<D_; d+=256) s += row[d]*aw[D_+d];
    s = blockReduceSum256(s);
    if (threadIdx.x==0) kdot[b] = s;
  } else if (b < N_*E_*M_ + D_){
    const int k = b - N_*E_*M_;
    const float* row = Wq + (size_t)k*D_;
    for (int d=threadIdx.x; d<D_; d+=256) s += row[d]*aw[d];
    s = blockReduceSum256(s);
    if (threadIdx.x==0) vq[k] = s;
  } else {
    for (int d=threadIdx.x; d<D_; d+=256) s += bq[d]*aw[d];
    s = blockReduceSum256(s);
    if (threadIdx.x==0) qc[0] = s + ab[0];
  }
}

// K7: qdot[r] = rs[r].vq + qc
__global__ __launch_bounds__(256) void k_qdot(const float* __restrict__ rs,
    const float* __restrict__ vq, const float* __restrict__ qc, float* __restrict__ qdot){
  const int r = blockIdx.x;
  float s = 0.f;
  for (int d=threadIdx.x; d<D_; d+=256) s += rs[(size_t)r*D_+d]*vq[d];
  s = blockReduceSum256(s);
  if (threadIdx.x==0) qdot[r] = s + qc[0];
}

// K8: hess/tess (bf16) = softmax-weighted KK rows
__global__ __launch_bounds__(256) void k_mention(const float* __restrict__ KK,
    const float* __restrict__ kdot, const float* __restrict__ qdot,
    const int* __restrict__ pos, const int* __restrict__ hts,
    __hip_bfloat16* __restrict__ hess, __hip_bfloat16* __restrict__ tess){
  const int b = blockIdx.x;
  const int side = b & 1;
  const int r = b >> 1;
  const int n = r >> 8;
  const int e = hts[r*2 + side];
  const int base = (n*E_ + e)*M_;
  const float q = qdot[r];
  float sc[M_];
  #pragma unroll
  for (int m=0;m<M_;m++){
    float s = q + kdot[base+m];
    s = (s > 0.f) ? s : 0.01f*s;
    sc[m] = (pos[base+m] != 0) ? s : -1e9f;
  }
  const float mx = fmaxf(fmaxf(sc[0],sc[1]), fmaxf(sc[2],sc[3]));
  float ex[M_]; float sum=0.f;
  #pragma unroll
  for (int m=0;m<M_;m++){ ex[m] = expf(sc[m]-mx); sum += ex[m]; }
  const float inv = 1.f/sum;
  __hip_bfloat16* outp = (side ? tess : hess) + (size_t)r*D_;
  const float* K0 = KK + (size_t)(base+0)*D_;
  const float* K1 = KK + (size_t)(base+1)*D_;
  const float* K2 = KK + (size_t)(base+2)*D_;
  const float* K3 = KK + (size_t)(base+3)*D_;
  const float p0=ex[0]*inv, p1=ex[1]*inv, p2=ex[2]*inv, p3=ex[3]*inv;
  for (int d=threadIdx.x; d<D_; d+=256)
    outp[d] = __float2bfloat16(p0*K0[d] + p1*K1[d] + p2*K2[d] + p3*K3[d]);
}

// K9: z GEMM (MFMA): zh/zt = act([rs|ent|hx] @ W + b)
__global__ __launch_bounds__(256) void k_gemm_z(
    const __hip_bfloat16* __restrict__ rs_bf, const __hip_bfloat16* __restrict__ ent_bf,
    const __hip_bfloat16* __restrict__ hess_bf, const __hip_bfloat16* __restrict__ tess_bf,
    const int* __restrict__ hts,
    const __hip_bfloat16* __restrict__ WhT, const __hip_bfloat16* __restrict__ WtT,
    const float* __restrict__ bh, const float* __restrict__ bt,
    float* __restrict__ zh, float* __restrict__ zt){
  const int side = blockIdx.z;
  const int bm = blockIdx.y*64, bn = blockIdx.x*64;
  const short* BT = (const short*)(side ? WtT : WhT);
  const float* bias = side ? bt : bh;
  float* Cm = side ? zt : zh;
  const short* hx  = (const short*)(side ? tess_bf : hess_bf);
  const short* rsp = (const short*)rs_bf;
  const short* enp = (const short*)ent_bf;
  __shared__ short As[64][40];
  __shared__ short Bs[64][40];
  __shared__ int e_s[64];
  const int tid = threadIdx.x;
  if (tid < 64) e_s[tid] = hts[(bm+tid)*2 + side];
  __syncthreads();
  const int w = tid>>6, l = tid&63;
  const int wm = w>>1, wn = w&1;
  const int lrow = tid>>2, lk8 = (tid&3)*8;
  const int arow = bm + lrow;
  const size_t eoff = ((size_t)(arow>>8)*E_ + e_s[lrow])*D_;
  f32x4 acc[2][2] = {};
  for (int k0=0;k0<K3D_;k0+=32){
    const int gk = k0 + lk8;
    const short* src;
    if (gk < D_)          src = &rsp[(size_t)arow*D_ + gk];
    else if (gk < 2*D_)   src = &enp[eoff + gk - D_];
    else                  src = &hx[(size_t)arow*D_ + gk - 2*D_];
    *(short8*)&As[lrow][lk8] = *(const short8*)src;
    *(short8*)&Bs[lrow][lk8] = *(const short8*)&BT[(size_t)(bn+lrow)*K3D_ + gk];
    __syncthreads();
    short8 af[2], bfv[2];
    #pragma unroll
    for (int f=0;f<2;f++){
      af[f]  = *(short8*)&As[wm*32+f*16+(l&15)][(l>>4)*8];
      bfv[f] = *(short8*)&Bs[wn*32+f*16+(l&15)][(l>>4)*8];
    }
    #pragma unroll
    for (int i=0;i<2;i++)
      #pragma unroll
      for (int j=0;j<2;j++)
        acc[i][j] = __builtin_amdgcn_mfma_f32_16x16x32_bf16(af[i], bfv[j], acc[i][j], 0,0,0);
    __syncthreads();
  }
  #pragma unroll
  for (int i=0;i<2;i++)
    #pragma unroll
    for (int j=0;j<2;j++)
      #pragma unroll
      for (int r=0;r<4;r++){
        const int row = bm + wm*32 + i*16 + (l>>4)*4 + r;
        const int col = bn + wn*32 + j*16 + (l&15);
        float v = acc[i][j][r] + bias[col];
        v = tanhf(v);
        if (side==0) v = tanhf(v);
        Cm[(size_t)row*D_ + col] = v;
      }
}

// K10: bilinear MFMA: partial[kc] = bl[:, kchunk] @ Wb[kchunk, :]
// bl generated on the fly: A[r][k] = zh[r][blk*64+i]*zt[r][blk*64+j]
__global__ __launch_bounds__(256) void k_bilinear(
    const float* __restrict__ zh, const float* __restrict__ zt,
    const __hip_bfloat16* __restrict__ WbT, float* __restrict__ partial){
  const int kc = blockIdx.x;          // 0..23
  const int blkI = kc >> 1, half = kc & 1;
  const int r0 = blockIdx.y*64;
  __shared__ float zh_s[64][36];
  __shared__ float zt_s[64][68];
  __shared__ short Bs[NLP_][40];
  const int tid = threadIdx.x;
  for (int idx=tid; idx<64*32; idx+=256){
    const int row = idx>>5, c = idx&31;
    zh_s[row][c] = zh[(size_t)(r0+row)*D_ + blkI*64 + half*32 + c];
  }
  for (int idx=tid; idx<64*64; idx+=256){
    const int row = idx>>6, c = idx&63;
    zt_s[row][c] = zt[(size_t)(r0+row)*D_ + blkI*64 + c];
  }
  const int w = tid>>6, l = tid&63;
  const int arow = w*16 + (l&15);
  const short* WT = (const short*)WbT;
  const size_t kbase = (size_t)blkI*4096 + half*2048;
  f32x4 acc[7] = {};
  for (int s=0;s<64;s++){
    for (int idx=tid; idx<NLP_*4; idx+=256){
      const int col = idx>>2, kkb = (idx&3)*8;
      *(short8*)&Bs[col][kkb] = *(const short8*)&WT[(size_t)col*KBL_ + kbase + s*32 + kkb];
    }
    __syncthreads();
    const int iLoc = s>>1;
    const int jj = (s&1)*32 + (l>>4)*8;
    const float a = zh_s[arow][iLoc];
    f32x4 z0 = *(f32x4*)&zt_s[arow][jj];
    f32x4 z1 = *(f32x4*)&zt_s[arow][jj+4];
    short8 afr;
    #pragma unroll
    for (int t=0;t<4;t++) afr[t]   = f2bf(a*z0[t]);
    #pragma unroll
    for (int t=0;t<4;t++) afr[4+t] = f2bf(a*z1[t]);
    #pragma unroll
    for (int nf=0;nf<7;nf++){
      const short8 bfr = *(short8*)&Bs[nf*16 + (l&15)][(l>>4)*8];
      acc[nf] = __builtin_amdgcn_mfma_f32_16x16x32_bf16(afr, bfr, acc[nf], 0,0,0);
    }
    __syncthreads();
  }
  #pragma unroll
  for (int nf=0;nf<7;nf++)
    #pragma unroll
    for (int r=0;r<4;r++){
      const int row = r0 + w*16 + (l>>4)*4 + r;
      const int col = nf*16 + (l&15);
      partial[((size_t)kc*NP_ + row)*NLP_ + col] = acc[nf][r];
    }
}

// K11: out = sum partials + bb
__global__ __launch_bounds__(256) void k_reduce(const float* __restrict__ partial,
    const float* __restrict__ bb, float* __restrict__ out){
  const int idx = blockIdx.x*256 + threadIdx.x;
  if (idx >= NP_*NL_) return;
  const int r = idx / NL_;
  const int l = idx - r*NL_;
  float s = bb[l];
  #pragma unroll
  for (int kc=0;kc<24;kc++) s += partial[((size_t)kc*NP_ + r)*NLP_ + l];
  out[idx] = s;
}

extern "C" void kernel_launch(void* const* d_in, const int* in_sizes, int n_in,
                              void* d_out, int out_size, void* d_ws, size_t ws_size,
                              hipStream_t stream){
  const float* seq  = (const float*)d_in[0];
  const float* attn = (const float*)d_in[1];
  const int*   pos  = (const int*)d_in[2];
  const int*   hts  = (const int*)d_in[3];
  const float* Wq = (const float*)d_in[4];
  const float* bq = (const float*)d_in[5];
  const float* Wk = (const float*)d_in[6];
  const float* bk = (const float*)d_in[7];
  const float* aw = (const float*)d_in[8];
  const float* ab = (const float*)d_in[9];
  const float* Wh = (const float*)d_in[10];
  const float* bh = (const float*)d_in[11];
  const float* Wt = (const float*)d_in[12];
  const float* bt = (const float*)d_in[13];
  const float* Wb = (const float*)d_in[14];
  const float* bb = (const float*)d_in[15];
  float* out = (float*)d_out;

  char* base = (char*)d_ws;
  size_t off = 0;
  auto alloc = [&](size_t bytes)->void*{
    void* p = base + off;
    off += (bytes + 255) & ~(size_t)255;
    return p;
  };
  __hip_bfloat16* WhT   = (__hip_bfloat16*)alloc((size_t)D_*K3D_*2);
  __hip_bfloat16* WtT   = (__hip_bfloat16*)alloc((size_t)D_*K3D_*2);
  __hip_bfloat16* WkT   = (__hip_bfloat16*)alloc((size_t)D_*D_*2);
  __hip_bfloat16* WbT   = (__hip_bfloat16*)alloc((size_t)NLP_*KBL_*2);
  __hip_bfloat16* seqT  = (__hip_bfloat16*)alloc((size_t)D_*N_*C_*2);
  __hip_bfloat16* ent_bf= (__hip_bfloat16*)alloc((size_t)N_*E_*D_*2);
  float* ent_att        = (float*)alloc((size_t)N_*E_*H_*C_*4);
  __hip_bfloat16* ht_bf = (__hip_bfloat16*)alloc((size_t)NP_*C_*2);
  __hip_bfloat16* Ambf  = (__hip_bfloat16*)alloc((size_t)N_*E_*M_*D_*2);
  float* KK             = (float*)alloc((size_t)N_*E_*M_*D_*4);
  float* kdot           = (float*)alloc(512*4);
  float* vq             = (float*)alloc(D_*4);
  float* qc             = (float*)alloc(256);
  float* qdot           = (float*)alloc(NP_*4);
  float* rs             = (float*)alloc((size_t)NP_*D_*4);
  __hip_bfloat16* rs_bf = (__hip_bfloat16*)alloc((size_t)NP_*D_*2);
  __hip_bfloat16* hess  = (__hip_bfloat16*)alloc((size_t)NP_*D_*2);
  __hip_bfloat16* tess  = (__hip_bfloat16*)alloc((size_t)NP_*D_*2);
  float* zh             = (float*)alloc((size_t)NP_*D_*4);
  float* zt             = (float*)alloc((size_t)NP_*D_*4);
  float* partial        = (float*)alloc((size_t)24*NP_*NLP_*4);
  (void)ws_size; (void)in_sizes; (void)n_in; (void)out_size;

  // transposed bf16 weight/operand prep
  k_tcvt<<<dim3(K3D_/32, D_/32), 256, 0, stream>>>(Wh, WhT, K3D_, D_, D_);
  k_tcvt<<<dim3(K3D_/32, D_/32), 256, 0, stream>>>(Wt, WtT, K3D_, D_, D_);
  k_tcvt<<<dim3(D_/32,  D_/32), 256, 0, stream>>>(Wk, WkT, D_, D_, D_);
  k_tcvt<<<dim3(KBL_/32, NLP_/32 + 1), 256, 0, stream>>>(Wb, WbT, KBL_, NL_, NLP_);
  k_tcvt<<<dim3((N_*C_)/32, D_/32), 256, 0, stream>>>(seq, seqT, N_*C_, D_, D_);

  k_ent_emb<<<N_*E_, 256, 0, stream>>>(seq, pos, ent_bf);
  k_ent_att<<<N_*E_*H_, 256, 0, stream>>>(attn, pos, ent_att);
  k_ht_att<<<NP_, 256, 0, stream>>>(ent_att, hts, ht_bf);
  k_gatherA<<<N_*E_*M_, 256, 0, stream>>>(seq, pos, Ambf);
  k_KKg<<<dim3(D_/64, (N_*E_*M_)/64), 256, 0, stream>>>(Ambf, WkT, bk, KK);
  k_gemm_rs<<<dim3(D_/64, P_/64, N_), 256, 0, stream>>>(ht_bf, seqT, rs, rs_bf);
  k_smalldots<<<N_*E_*M_ + D_ + 1, 256, 0, stream>>>(KK, aw, ab, Wq, bq, kdot, vq, qc);
  k_qdot<<<NP_, 256, 0, stream>>>(rs, vq, qc, qdot);
  k_mention<<<NP_*2, 256, 0, stream>>>(KK, kdot, qdot, pos, hts, hess, tess);
  k_gemm_z<<<dim3(D_/64, NP_/64, 2), 256, 0, stream>>>(rs_bf, ent_bf, hess, tess, hts,
                                                       WhT, WtT, bh, bt, zh, zt);
  k_bilinear<<<dim3(24, NP_/64), 256, 0, stream>>>(zh, zt, WbT, partial);
  k_reduce<<<(NP_*NL_+255)/256, 256, 0, stream>>>(partial, bb, out);
}

// Round 3
// 147.092 us; speedup vs baseline: 6.2556x; 1.2131x over previous
//
#include <hip/hip_runtime.h>
#include <hip/hip_bf16.h>
#include <math.h>

#define N_ 4
#define C_ 1024
#define D_ 768
#define H_ 12
#define E_ 32
#define M_ 4
#define P_ 256
#define NL_ 97
#define NLP_ 112
#define NP_ (N_*P_)
#define K3D_ 2304
#define KBL_ 49152

typedef __attribute__((ext_vector_type(8))) short short8;
typedef __attribute__((ext_vector_type(4))) float f32x4;

__device__ __forceinline__ short f2bf(float x){
  union { __hip_bfloat16 h; short s; } u; u.h = __float2bfloat16(x); return u.s;
}

__device__ __forceinline__ float blockReduceSum256(float v){
  __shared__ float red_s[4];
  #pragma unroll
  for (int o=32;o>0;o>>=1) v += __shfl_down(v, o);
  if ((threadIdx.x & 63)==0) red_s[threadIdx.x>>6] = v;
  __syncthreads();
  float t = red_s[0]+red_s[1]+red_s[2]+red_s[3];
  __syncthreads();
  return t;
}

// transpose+cvt tile: in [R][C] f32 -> out [Cp][R] bf16 (zero-pad cols >= C)
__device__ __forceinline__ void tcvt_tile(const float* __restrict__ in,
    __hip_bfloat16* __restrict__ out, int R, int C, int Cp, int tile){
  __shared__ float tbuf[32][33];
  const int tiles_c = (Cp+31)>>5;
  const int rb = (tile/tiles_c)*32, cb = (tile%tiles_c)*32;
  const int tx = threadIdx.x & 31, ty = threadIdx.x >> 5;
  #pragma unroll
  for (int i=0;i<4;i++){
    const int r = ty + i*8, c = cb + tx;
    tbuf[r][tx] = (c < C) ? in[(size_t)(rb+r)*C + c] : 0.f;
  }
  __syncthreads();
  #pragma unroll
  for (int i=0;i<4;i++){
    const int cr = ty + i*8, cc = cb + cr;
    if (cc < Cp) out[(size_t)cc*R + rb + tx] = __float2bfloat16(tbuf[tx][cr]);
  }
}

// prep mega-kernel block ranges
#define GB_WH 1728          // (2304/32)*(768/32)
#define GB_WT 1728
#define GB_WK 576           // 24*24
#define GB_WB 6144          // (49152/32)*ceil(112/32)
#define GB_SEQ 3072         // (4096/32)*(768/32)
#define O_WT  (GB_WH)
#define O_WK  (O_WT+GB_WT)
#define O_WB  (O_WK+GB_WK)
#define O_SEQ (O_WB+GB_WB)
#define O_EMB (O_SEQ+GB_SEQ)
#define O_ATT (O_EMB+N_*E_)
#define O_VQ  (O_ATT+N_*E_*H_)
#define O_QC  (O_VQ+D_)
#define G_PREP (O_QC+1)

__global__ __launch_bounds__(256) void k_prep(
    const float* __restrict__ seq, const float* __restrict__ attn,
    const int* __restrict__ pos,
    const float* __restrict__ Wq, const float* __restrict__ bq,
    const float* __restrict__ Wk, const float* __restrict__ aw,
    const float* __restrict__ ab,
    const float* __restrict__ Wh, const float* __restrict__ Wt,
    const float* __restrict__ Wb,
    __hip_bfloat16* __restrict__ WhT, __hip_bfloat16* __restrict__ WtT,
    __hip_bfloat16* __restrict__ WkT, __hip_bfloat16* __restrict__ WbT,
    __hip_bfloat16* __restrict__ seqT,
    __hip_bfloat16* __restrict__ ent_bf, __hip_bfloat16* __restrict__ Ambf,
    float* __restrict__ ent_att, float* __restrict__ vq, float* __restrict__ qc){
  const int b = blockIdx.x;
  const int tid = threadIdx.x;
  if (b < O_WT){ tcvt_tile(Wh, WhT, K3D_, D_, D_, b); return; }
  if (b < O_WK){ tcvt_tile(Wt, WtT, K3D_, D_, D_, b-O_WT); return; }
  if (b < O_WB){ tcvt_tile(Wk, WkT, D_, D_, D_, b-O_WK); return; }
  if (b < O_SEQ){ tcvt_tile(Wb, WbT, KBL_, NL_, NLP_, b-O_WB); return; }
  if (b < O_EMB){ tcvt_tile(seq, seqT, N_*C_, D_, D_, b-O_SEQ); return; }
  if (b < O_ATT){
    // ent_emb (logsumexp over 4 mention rows) + mention-row gather to bf16
    const int be = b - O_EMB;
    const int n = be >> 5;
    const int* pp = pos + be*M_;
    const float* s0 = seq + ((size_t)n*C_ + pp[0])*D_;
    const float* s1 = seq + ((size_t)n*C_ + pp[1])*D_;
    const float* s2 = seq + ((size_t)n*C_ + pp[2])*D_;
    const float* s3 = seq + ((size_t)n*C_ + pp[3])*D_;
    for (int d=tid; d<D_; d+=256){
      float v0=s0[d], v1=s1[d], v2=s2[d], v3=s3[d];
      Ambf[(size_t)(be*4+0)*D_ + d] = __float2bfloat16(v0);
      Ambf[(size_t)(be*4+1)*D_ + d] = __float2bfloat16(v1);
      Ambf[(size_t)(be*4+2)*D_ + d] = __float2bfloat16(v2);
      Ambf[(size_t)(be*4+3)*D_ + d] = __float2bfloat16(v3);
      float m = fmaxf(fmaxf(v0,v1), fmaxf(v2,v3));
      float s = expf(v0-m)+expf(v1-m)+expf(v2-m)+expf(v3-m);
      ent_bf[(size_t)be*D_ + d] = __float2bfloat16(m + logf(s));
    }
    return;
  }
  if (b < O_VQ){
    const int bb2 = b - O_ATT;          // (n*E+e)*H + h
    const int h = bb2 % H_;
    const int ne = bb2 / H_;
    const int n = ne >> 5;
    const int* pp = pos + ne*M_;
    const float* base = attn + ((size_t)(n*H_+h))*C_*C_;
    const float* r0 = base + (size_t)pp[0]*C_;
    const float* r1 = base + (size_t)pp[1]*C_;
    const float* r2 = base + (size_t)pp[2]*C_;
    const float* r3 = base + (size_t)pp[3]*C_;
    float* outp = ent_att + (size_t)bb2*C_;
    for (int c=tid; c<C_; c+=256)
      outp[c] = 0.25f*(r0[c]+r1[c]+r2[c]+r3[c]);
    return;
  }
  if (b < O_QC){
    const int k = b - O_VQ;
    float s = 0.f;
    for (int d=tid; d<D_; d+=256) s += Wq[(size_t)k*D_+d]*aw[d];
    s = blockReduceSum256(s);
    if (tid==0) vq[k] = s;
    return;
  }
  {
    float s = 0.f;
    for (int d=tid; d<D_; d+=256) s += bq[d]*aw[d];
    s = blockReduceSum256(s);
    if (tid==0) qc[0] = s + ab[0];
  }
}

// ht_att (bf16 out) — needs full ent_att
__global__ __launch_bounds__(256) void k_ht_att(const float* __restrict__ ent_att,
    const int* __restrict__ hts, __hip_bfloat16* __restrict__ ht_bf){
  const int r = blockIdx.x;
  const int n = r >> 8;
  const int he = hts[r*2], te = hts[r*2+1];
  const float* ha = ent_att + ((size_t)(n*E_+he))*H_*C_;
  const float* ta = ent_att + ((size_t)(n*E_+te))*H_*C_;
  float vals[4]; float local = 0.f;
  #pragma unroll
  for (int u=0;u<4;u++){
    const int c = threadIdx.x + u*256;
    float acc = 0.f;
    #pragma unroll
    for (int h=0;h<H_;h++) acc = fmaf(ha[h*C_+c], ta[h*C_+c], acc);
    vals[u] = acc * (1.0f/H_);
    local += vals[u];
  }
  const float tot = blockReduceSum256(local);
  const float den = tot + 1e-5f;
  #pragma unroll
  for (int u=0;u<4;u++)
    ht_bf[(size_t)r*C_ + threadIdx.x + u*256] = __float2bfloat16(vals[u]/den);
}

// fused GEMM1: blocks [0,96): KK = Ambf @ WkT + bk ; [96,288): rs = ht @ seqT
__global__ __launch_bounds__(256) void k_gemm1(
    const __hip_bfloat16* __restrict__ Ambf, const __hip_bfloat16* __restrict__ WkT,
    const float* __restrict__ bk, float* __restrict__ KK,
    const __hip_bfloat16* __restrict__ ht_bf, const __hip_bfloat16* __restrict__ seqT,
    float* __restrict__ rs, __hip_bfloat16* __restrict__ rs_bf){
  __shared__ short As[64][72];
  __shared__ short Bs[64][72];
  const int tid = threadIdx.x;
  const int w = tid>>6, l = tid&63, wm = w>>1, wn = w&1;
  const short *Ap, *Bp;
  int lda, ldb, K, bm, bn;
  bool isKK;
  if (blockIdx.x < 96){
    isKK = true;
    bm = (blockIdx.x/12)*64; bn = (blockIdx.x%12)*64;
    Ap = (const short*)Ambf + (size_t)bm*D_; lda = D_; K = D_;
    Bp = (const short*)WkT + (size_t)bn*D_;  ldb = D_;
  } else {
    isKK = false;
    const int z = blockIdx.x - 96;
    const int n = z/48, rem = z%48, bmI = rem/12, bnI = rem%12;
    bm = n*P_ + bmI*64; bn = bnI*64;
    Ap = (const short*)ht_bf + (size_t)bm*C_;            lda = C_;     K = C_;
    Bp = (const short*)seqT + (size_t)bn*(N_*C_) + n*C_; ldb = N_*C_;
  }
  f32x4 acc[2][2] = {};
  for (int k0=0;k0<K;k0+=64){
    #pragma unroll
    for (int t=0;t<2;t++){
      const int idx = tid + t*256;
      const int row = idx>>3, k8 = (idx&7)*8;
      *(short8*)&As[row][k8] = *(const short8*)&Ap[(size_t)row*lda + k0 + k8];
      *(short8*)&Bs[row][k8] = *(const short8*)&Bp[(size_t)row*ldb + k0 + k8];
    }
    __syncthreads();
    #pragma unroll
    for (int h=0;h<2;h++){
      short8 af[2], bfv[2];
      #pragma unroll
      for (int f=0;f<2;f++){
        af[f]  = *(short8*)&As[wm*32+f*16+(l&15)][h*32+(l>>4)*8];
        bfv[f] = *(short8*)&Bs[wn*32+f*16+(l&15)][h*32+(l>>4)*8];
      }
      #pragma unroll
      for (int i=0;i<2;i++)
        #pragma unroll
        for (int j=0;j<2;j++)
          acc[i][j] = __builtin_amdgcn_mfma_f32_16x16x32_bf16(af[i], bfv[j], acc[i][j], 0,0,0);
    }
    __syncthreads();
  }
  #pragma unroll
  for (int i=0;i<2;i++)
    #pragma unroll
    for (int j=0;j<2;j++)
      #pragma unroll
      for (int r_=0;r_<4;r_++){
        const int row = bm + wm*32 + i*16 + (l>>4)*4 + r_;
        const int col = bn + wn*32 + j*16 + (l&15);
        const float v = acc[i][j][r_];
        if (isKK){
          KK[(size_t)row*D_ + col] = v + bk[col];
        } else {
          rs[(size_t)row*D_ + col] = v;
          rs_bf[(size_t)row*D_ + col] = __float2bfloat16(v);
        }
      }
}

// fused qdot + kdot + mention softmax-blend
__global__ __launch_bounds__(256) void k_mention(
    const float* __restrict__ rs, const float* __restrict__ KK,
    const float* __restrict__ vq, const float* __restrict__ qc,
    const float* __restrict__ aw, const int* __restrict__ pos,
    const int* __restrict__ hts,
    __hip_bfloat16* __restrict__ hess, __hip_bfloat16* __restrict__ tess){
  const int r = blockIdx.x, n = r>>8, tid = threadIdx.x;
  float s = 0.f;
  for (int d=tid; d<D_; d+=256) s += rs[(size_t)r*D_+d]*vq[d];
  const float q = blockReduceSum256(s) + qc[0];
  #pragma unroll
  for (int side=0;side<2;side++){
    const int e = hts[r*2+side];
    const int base = (n*E_+e)*M_;
    float part[4] = {0,0,0,0};
    for (int d=tid; d<D_; d+=256){
      const float a2 = aw[D_+d];
      #pragma unroll
      for (int m=0;m<4;m++) part[m] += KK[(size_t)(base+m)*D_+d]*a2;
    }
    float sc[4];
    #pragma unroll
    for (int m=0;m<4;m++){
      float t = q + blockReduceSum256(part[m]);
      t = (t > 0.f) ? t : 0.01f*t;
      sc[m] = (pos[base+m] != 0) ? t : -1e9f;
    }
    const float mx = fmaxf(fmaxf(sc[0],sc[1]), fmaxf(sc[2],sc[3]));
    float ex[4]; float sum = 0.f;
    #pragma unroll
    for (int m=0;m<4;m++){ ex[m] = expf(sc[m]-mx); sum += ex[m]; }
    const float inv = 1.f/sum;
    const float p0=ex[0]*inv, p1=ex[1]*inv, p2=ex[2]*inv, p3=ex[3]*inv;
    const float* K0 = KK + (size_t)(base+0)*D_;
    const float* K1 = KK + (size_t)(base+1)*D_;
    const float* K2 = KK + (size_t)(base+2)*D_;
    const float* K3 = KK + (size_t)(base+3)*D_;
    __hip_bfloat16* outp = (side ? tess : hess) + (size_t)r*D_;
    for (int d=tid; d<D_; d+=256)
      outp[d] = __float2bfloat16(p0*K0[d] + p1*K1[d] + p2*K2[d] + p3*K3[d]);
  }
}

// z GEMM, BK=64, gather-fused A
__global__ __launch_bounds__(256) void k_gemm_z(
    const __hip_bfloat16* __restrict__ rs_bf, const __hip_bfloat16* __restrict__ ent_bf,
    const __hip_bfloat16* __restrict__ hess_bf, const __hip_bfloat16* __restrict__ tess_bf,
    const int* __restrict__ hts,
    const __hip_bfloat16* __restrict__ WhT, const __hip_bfloat16* __restrict__ WtT,
    const float* __restrict__ bh, const float* __restrict__ bt,
    float* __restrict__ zh, float* __restrict__ zt){
  const int side = blockIdx.z;
  const int bm = blockIdx.y*64, bn = blockIdx.x*64;
  const short* BT = (const short*)(side ? WtT : WhT);
  const float* bias = side ? bt : bh;
  float* Cm = side ? zt : zh;
  const short* hx  = (const short*)(side ? tess_bf : hess_bf);
  const short* rsp = (const short*)rs_bf;
  const short* enp = (const short*)ent_bf;
  __shared__ short As[64][72];
  __shared__ short Bs[64][72];
  __shared__ int e_s[64];
  const int tid = threadIdx.x;
  if (tid < 64) e_s[tid] = hts[(bm+tid)*2 + side];
  __syncthreads();
  const int w = tid>>6, l = tid&63, wm = w>>1, wn = w&1;
  f32x4 acc[2][2] = {};
  for (int k0=0;k0<K3D_;k0+=64){
    #pragma unroll
    for (int t=0;t<2;t++){
      const int idx = tid + t*256;
      const int row = idx>>3, k8 = (idx&7)*8;
      const int arow = bm + row;
      const int gk = k0 + k8;
      const short* src;
      if (gk < D_)        src = &rsp[(size_t)arow*D_ + gk];
      else if (gk < 2*D_) src = &enp[((size_t)(arow>>8)*E_ + e_s[row])*D_ + gk - D_];
      else                src = &hx[(size_t)arow*D_ + gk - 2*D_];
      *(short8*)&As[row][k8] = *(const short8*)src;
      *(short8*)&Bs[row][k8] = *(const short8*)&BT[(size_t)(bn+row)*K3D_ + gk];
    }
    __syncthreads();
    #pragma unroll
    for (int h=0;h<2;h++){
      short8 af[2], bfv[2];
      #pragma unroll
      for (int f=0;f<2;f++){
        af[f]  = *(short8*)&As[wm*32+f*16+(l&15)][h*32+(l>>4)*8];
        bfv[f] = *(short8*)&Bs[wn*32+f*16+(l&15)][h*32+(l>>4)*8];
      }
      #pragma unroll
      for (int i=0;i<2;i++)
        #pragma unroll
        for (int j=0;j<2;j++)
          acc[i][j] = __builtin_amdgcn_mfma_f32_16x16x32_bf16(af[i], bfv[j], acc[i][j], 0,0,0);
    }
    __syncthreads();
  }
  #pragma unroll
  for (int i=0;i<2;i++)
    #pragma unroll
    for (int j=0;j<2;j++)
      #pragma unroll
      for (int r_=0;r_<4;r_++){
        const int row = bm + wm*32 + i*16 + (l>>4)*4 + r_;
        const int col = bn + wn*32 + j*16 + (l&15);
        float v = acc[i][j][r_] + bias[col];
        v = tanhf(v);
        if (side==0) v = tanhf(v);
        Cm[(size_t)row*D_ + col] = v;
      }
}

// bilinear MFMA: 4 s-steps per barrier pair + register prefetch of next B-group
__global__ __launch_bounds__(256) void k_bilinear(
    const float* __restrict__ zh, const float* __restrict__ zt,
    const __hip_bfloat16* __restrict__ WbT, float* __restrict__ partial){
  const int kc = blockIdx.x;          // 0..23
  const int blkI = kc >> 1, half = kc & 1;
  const int r0 = blockIdx.y*64;
  __shared__ float zh_s[64][36];
  __shared__ float zt_s[64][68];
  __shared__ short Bs[4][NLP_][40];
  const int tid = threadIdx.x;
  for (int idx=tid; idx<64*32; idx+=256){
    const int row = idx>>5, c = idx&31;
    zh_s[row][c] = zh[(size_t)(r0+row)*D_ + blkI*64 + half*32 + c];
  }
  for (int idx=tid; idx<64*64; idx+=256){
    const int row = idx>>6, c = idx&63;
    zt_s[row][c] = zt[(size_t)(r0+row)*D_ + blkI*64 + c];
  }
  const int w = tid>>6, l = tid&63;
  const int arow = w*16 + (l&15);
  const short* WT = (const short*)WbT;
  const size_t kbase = (size_t)blkI*4096 + half*2048;
  // this thread's 7 staging chunks (4 s-steps x 112 cols x 4 k8-chunks = 1792 / 256)
  int sl[7], cl[7], k8l[7];
  #pragma unroll
  for (int t=0;t<7;t++){
    const int ci = tid + t*256;
    sl[t] = ci/448;
    const int rem = ci - sl[t]*448;
    cl[t] = rem>>2; k8l[t] = (rem&3)*8;
  }
  short8 pre[7];
  #pragma unroll
  for (int t=0;t<7;t++)
    pre[t] = *(const short8*)&WT[(size_t)cl[t]*KBL_ + kbase + (size_t)sl[t]*32 + k8l[t]];
  f32x4 acc[7] = {};
  for (int g=0; g<16; ++g){
    __syncthreads();                    // previous group's Bs reads done
    #pragma unroll
    for (int t=0;t<7;t++) *(short8*)&Bs[sl[t]][cl[t]][k8l[t]] = pre[t];
    __syncthreads();
    if (g < 15){
      #pragma unroll
      for (int t=0;t<7;t++)
        pre[t] = *(const short8*)&WT[(size_t)cl[t]*KBL_ + kbase + (size_t)((g+1)*4+sl[t])*32 + k8l[t]];
    }
    #pragma unroll
    for (int ss=0;ss<4;ss++){
      const int s = g*4 + ss;
      const int iLoc = s>>1;
      const int jj = (s&1)*32 + (l>>4)*8;
      const float a = zh_s[arow][iLoc];
      f32x4 z0 = *(f32x4*)&zt_s[arow][jj];
      f32x4 z1 = *(f32x4*)&zt_s[arow][jj+4];
      short8 afr;
      #pragma unroll
      for (int t=0;t<4;t++) afr[t]   = f2bf(a*z0[t]);
      #pragma unroll
      for (int t=0;t<4;t++) afr[4+t] = f2bf(a*z1[t]);
      #pragma unroll
      for (int nf=0;nf<7;nf++){
        const short8 bfr = *(short8*)&Bs[ss][nf*16 + (l&15)][(l>>4)*8];
        acc[nf] = __builtin_amdgcn_mfma_f32_16x16x32_bf16(afr, bfr, acc[nf], 0,0,0);
      }
    }
  }
  #pragma unroll
  for (int nf=0;nf<7;nf++)
    #pragma unroll
    for (int r_=0;r_<4;r_++){
      const int row = r0 + w*16 + (l>>4)*4 + r_;
      const int col = nf*16 + (l&15);
      partial[((size_t)kc*NP_ + row)*NLP_ + col] = acc[nf][r_];
    }
}

__global__ __launch_bounds__(256) void k_reduce(const float* __restrict__ partial,
    const float* __restrict__ bb, float* __restrict__ out){
  const int idx = blockIdx.x*256 + threadIdx.x;
  if (idx >= NP_*NL_) return;
  const int r = idx / NL_;
  const int l = idx - r*NL_;
  float s = bb[l];
  #pragma unroll
  for (int kc=0;kc<24;kc++) s += partial[((size_t)kc*NP_ + r)*NLP_ + l];
  out[idx] = s;
}

extern "C" void kernel_launch(void* const* d_in, const int* in_sizes, int n_in,
                              void* d_out, int out_size, void* d_ws, size_t ws_size,
                              hipStream_t stream){
  const float* seq  = (const float*)d_in[0];
  const float* attn = (const float*)d_in[1];
  const int*   pos  = (const int*)d_in[2];
  const int*   hts  = (const int*)d_in[3];
  const float* Wq = (const float*)d_in[4];
  const float* bq = (const float*)d_in[5];
  const float* Wk = (const float*)d_in[6];
  const float* bk = (const float*)d_in[7];
  const float* aw = (const float*)d_in[8];
  const float* ab = (const float*)d_in[9];
  const float* Wh = (const float*)d_in[10];
  const float* bh = (const float*)d_in[11];
  const float* Wt = (const float*)d_in[12];
  const float* bt = (const float*)d_in[13];
  const float* Wb = (const float*)d_in[14];
  const float* bb = (const float*)d_in[15];
  float* out = (float*)d_out;

  char* base = (char*)d_ws;
  size_t off = 0;
  auto alloc = [&](size_t bytes)->void*{
    void* p = base + off;
    off += (bytes + 255) & ~(size_t)255;
    return p;
  };
  __hip_bfloat16* WhT   = (__hip_bfloat16*)alloc((size_t)D_*K3D_*2);
  __hip_bfloat16* WtT   = (__hip_bfloat16*)alloc((size_t)D_*K3D_*2);
  __hip_bfloat16* WkT   = (__hip_bfloat16*)alloc((size_t)D_*D_*2);
  __hip_bfloat16* WbT   = (__hip_bfloat16*)alloc((size_t)NLP_*KBL_*2);
  __hip_bfloat16* seqT  = (__hip_bfloat16*)alloc((size_t)D_*N_*C_*2);
  __hip_bfloat16* ent_bf= (__hip_bfloat16*)alloc((size_t)N_*E_*D_*2);
  float* ent_att        = (float*)alloc((size_t)N_*E_*H_*C_*4);
  __hip_bfloat16* ht_bf = (__hip_bfloat16*)alloc((size_t)NP_*C_*2);
  __hip_bfloat16* Ambf  = (__hip_bfloat16*)alloc((size_t)N_*E_*M_*D_*2);
  float* KK             = (float*)alloc((size_t)N_*E_*M_*D_*4);
  float* vq             = (float*)alloc(D_*4);
  float* qc             = (float*)alloc(256);
  float* rs             = (float*)alloc((size_t)NP_*D_*4);
  __hip_bfloat16* rs_bf = (__hip_bfloat16*)alloc((size_t)NP_*D_*2);
  __hip_bfloat16* hess  = (__hip_bfloat16*)alloc((size_t)NP_*D_*2);
  __hip_bfloat16* tess  = (__hip_bfloat16*)alloc((size_t)NP_*D_*2);
  float* zh             = (float*)alloc((size_t)NP_*D_*4);
  float* zt             = (float*)alloc((size_t)NP_*D_*4);
  float* partial        = (float*)alloc((size_t)24*NP_*NLP_*4);
  (void)ws_size; (void)in_sizes; (void)n_in; (void)out_size;

  k_prep<<<G_PREP, 256, 0, stream>>>(seq, attn, pos, Wq, bq, Wk, aw, ab, Wh, Wt, Wb,
                                     WhT, WtT, WkT, WbT, seqT, ent_bf, Ambf, ent_att, vq, qc);
  k_ht_att<<<NP_, 256, 0, stream>>>(ent_att, hts, ht_bf);
  k_gemm1<<<288, 256, 0, stream>>>(Ambf, WkT, bk, KK, ht_bf, seqT, rs, rs_bf);
  k_mention<<<NP_, 256, 0, stream>>>(rs, KK, vq, qc, aw, pos, hts, hess, tess);
  k_gemm_z<<<dim3(D_/64, NP_/64, 2), 256, 0, stream>>>(rs_bf, ent_bf, hess, tess, hts,
                                                       WhT, WtT, bh, bt, zh, zt);
  k_bilinear<<<dim3(24, NP_/64), 256, 0, stream>>>(zh, zt, WbT, partial);
  k_reduce<<<(NP_*NL_+255)/256, 256, 0, stream>>>(partial, bb, out);
}

// Round 5
// 105.495 us; speedup vs baseline: 8.7223x; 1.3943x over previous
//
#include <hip/hip_runtime.h>
#include <hip/hip_bf16.h>
#include <math.h>

#define N_ 4
#define C_ 1024
#define D_ 768
#define H_ 12
#define E_ 32
#define M_ 4
#define P_ 256
#define NL_ 97
#define NLP_ 112
#define NP_ (N_*P_)
#define K3D_ 2304
#define KBL_ 49152

typedef __attribute__((ext_vector_type(8))) short short8;
typedef __attribute__((ext_vector_type(4))) float f32x4;
typedef __attribute__((ext_vector_type(4))) unsigned short ushort4v;

__device__ __forceinline__ short f2bf(float x){
  union { __hip_bfloat16 h; short s; } u; u.h = __float2bfloat16(x); return u.s;
}
__device__ __forceinline__ unsigned short f2bfu(float x){
  union { __hip_bfloat16 h; unsigned short s; } u; u.h = __float2bfloat16(x); return u.s;
}
__device__ __forceinline__ float bf2f(unsigned short u){
  union { unsigned int i; float f; } x; x.i = ((unsigned int)u)<<16; return x.f;
}

__device__ __forceinline__ float blockReduceSum256(float v){
  __shared__ float red_s[4];
  #pragma unroll
  for (int o=32;o>0;o>>=1) v += __shfl_down(v, o);
  if ((threadIdx.x & 63)==0) red_s[threadIdx.x>>6] = v;
  __syncthreads();
  float t = red_s[0]+red_s[1]+red_s[2]+red_s[3];
  __syncthreads();
  return t;
}

// transpose+cvt 64(R)x32(C) tile: in [R][C] f32 -> out [Cp][R] bf16, zero-pad c>=C
// tiles_c = ceil(Cp/32)  (FIX vs round 4: was Cp>>5, OOB for Cp=112)
__device__ __forceinline__ void tcvt64(const float* __restrict__ in,
    __hip_bfloat16* __restrict__ out, int R, int C, int Cp, int tile){
  __shared__ float tb[64][33];
  const int tiles_c = (Cp + 31) >> 5;
  const int rb = (tile/tiles_c)*64, cb = (tile%tiles_c)*32;
  const int tid = threadIdx.x;
  const bool vec = ((C & 3) == 0);
  #pragma unroll
  for (int i=0;i<2;i++){
    const int idx = tid + i*256;
    const int row = idx>>3, c4 = (idx&7)*4;
    const int c = cb + c4;
    float v0=0.f,v1=0.f,v2=0.f,v3=0.f;
    if (vec && c+3 < C){
      const f32x4 v = *(const f32x4*)&in[(size_t)(rb+row)*C + c];
      v0=v[0]; v1=v[1]; v2=v[2]; v3=v[3];
    } else {
      const float* rp = in + (size_t)(rb+row)*C;
      if (c   < C) v0 = rp[c];
      if (c+1 < C) v1 = rp[c+1];
      if (c+2 < C) v2 = rp[c+2];
      if (c+3 < C) v3 = rp[c+3];
    }
    tb[row][c4]=v0; tb[row][c4+1]=v1; tb[row][c4+2]=v2; tb[row][c4+3]=v3;
  }
  __syncthreads();
  #pragma unroll
  for (int i=0;i<4;i++){
    const int idx = tid + i*256;
    const int cr = idx>>5, p = idx&31;
    const int cc = cb + cr;
    if (cc < Cp){
      union { struct { unsigned short a,b; } s; unsigned int u; } pk;
      pk.s.a = f2bfu(tb[2*p][cr]);
      pk.s.b = f2bfu(tb[2*p+1][cr]);
      *(unsigned int*)&out[(size_t)cc*R + rb + 2*p] = pk.u;
    }
  }
}

// prep block ranges (tiles_c = ceil(Cp/32) everywhere)
#define T_WH 864            // (2304/64)*24
#define T_WT 864
#define T_WK 288            // (768/64)*24
#define T_WB 3072           // (49152/64)*4   (ceil(112/32)=4)
#define T_SEQ 1536          // (4096/64)*24
#define O_WT  (T_WH)
#define O_WK  (O_WT+T_WT)
#define O_WB  (O_WK+T_WK)
#define O_SEQ (O_WB+T_WB)
#define O_EMB (O_SEQ+T_SEQ)
#define O_ATT (O_EMB+N_*E_)
#define O_VQ  (O_ATT+N_*E_*H_)
#define O_WKAW (O_VQ+D_)
#define O_MISC (O_WKAW+D_)
#define G_PREP (O_MISC+1)

__global__ __launch_bounds__(256) void k_prep(
    const float* __restrict__ seq, const float* __restrict__ attn,
    const int* __restrict__ pos,
    const float* __restrict__ Wq, const float* __restrict__ bq,
    const float* __restrict__ Wk, const float* __restrict__ bk,
    const float* __restrict__ aw, const float* __restrict__ ab,
    const float* __restrict__ Wh, const float* __restrict__ Wt,
    const float* __restrict__ Wb,
    __hip_bfloat16* __restrict__ WhT, __hip_bfloat16* __restrict__ WtT,
    __hip_bfloat16* __restrict__ WkT, __hip_bfloat16* __restrict__ WbT,
    __hip_bfloat16* __restrict__ seqT,
    __hip_bfloat16* __restrict__ ent_bf, __hip_bfloat16* __restrict__ Ambf,
    __hip_bfloat16* __restrict__ att_bf,
    float* __restrict__ vq, float* __restrict__ wk_aw, float* __restrict__ qc2){
  const int b = blockIdx.x;
  const int tid = threadIdx.x;
  if (b < O_WT){ tcvt64(Wh, WhT, K3D_, D_, D_, b); return; }
  if (b < O_WK){ tcvt64(Wt, WtT, K3D_, D_, D_, b-O_WT); return; }
  if (b < O_WB){ tcvt64(Wk, WkT, D_, D_, D_, b-O_WK); return; }
  if (b < O_SEQ){ tcvt64(Wb, WbT, KBL_, NL_, NLP_, b-O_WB); return; }
  if (b < O_EMB){ tcvt64(seq, seqT, N_*C_, D_, D_, b-O_SEQ); return; }
  if (b < O_ATT){
    // ent_emb (logsumexp) + mention-row gather to bf16
    const int be = b - O_EMB;
    const int n = be >> 5;
    const int* pp = pos + be*M_;
    if (tid < 192){
      const int c4 = tid*4;
      const f32x4 v0 = *(const f32x4*)&seq[((size_t)n*C_ + pp[0])*D_ + c4];
      const f32x4 v1 = *(const f32x4*)&seq[((size_t)n*C_ + pp[1])*D_ + c4];
      const f32x4 v2 = *(const f32x4*)&seq[((size_t)n*C_ + pp[2])*D_ + c4];
      const f32x4 v3 = *(const f32x4*)&seq[((size_t)n*C_ + pp[3])*D_ + c4];
      ushort4v a0,a1,a2,a3,e;
      #pragma unroll
      for (int j=0;j<4;j++){
        a0[j]=f2bfu(v0[j]); a1[j]=f2bfu(v1[j]); a2[j]=f2bfu(v2[j]); a3[j]=f2bfu(v3[j]);
        const float m = fmaxf(fmaxf(v0[j],v1[j]), fmaxf(v2[j],v3[j]));
        const float s = expf(v0[j]-m)+expf(v1[j]-m)+expf(v2[j]-m)+expf(v3[j]-m);
        e[j] = f2bfu(m + logf(s));
      }
      *(ushort4v*)&Ambf[(size_t)(be*4+0)*D_ + c4] = a0;
      *(ushort4v*)&Ambf[(size_t)(be*4+1)*D_ + c4] = a1;
      *(ushort4v*)&Ambf[(size_t)(be*4+2)*D_ + c4] = a2;
      *(ushort4v*)&Ambf[(size_t)(be*4+3)*D_ + c4] = a3;
      *(ushort4v*)&ent_bf[(size_t)be*D_ + c4] = e;
    }
    return;
  }
  if (b < O_VQ){
    const int bb2 = b - O_ATT;          // (n*E+e)*H + h
    const int h = bb2 % H_;
    const int ne = bb2 / H_;
    const int n = ne >> 5;
    const int* pp = pos + ne*M_;
    const float* basep = attn + ((size_t)(n*H_+h))*C_*C_;
    const int c4 = tid*4;
    const f32x4 r0 = *(const f32x4*)&basep[(size_t)pp[0]*C_ + c4];
    const f32x4 r1 = *(const f32x4*)&basep[(size_t)pp[1]*C_ + c4];
    const f32x4 r2 = *(const f32x4*)&basep[(size_t)pp[2]*C_ + c4];
    const f32x4 r3 = *(const f32x4*)&basep[(size_t)pp[3]*C_ + c4];
    ushort4v o;
    #pragma unroll
    for (int j=0;j<4;j++) o[j] = f2bfu(0.25f*(r0[j]+r1[j]+r2[j]+r3[j]));
    *(ushort4v*)&att_bf[(size_t)bb2*C_ + c4] = o;
    return;
  }
  if (b < O_WKAW){
    const int k = b - O_VQ;
    float s = 0.f;
    for (int d=tid; d<D_; d+=256) s += Wq[(size_t)k*D_+d]*aw[d];
    s = blockReduceSum256(s);
    if (tid==0) vq[k] = s;
    return;
  }
  if (b < O_MISC){
    const int k = b - O_WKAW;
    float s = 0.f;
    for (int d=tid; d<D_; d+=256) s += Wk[(size_t)k*D_+d]*aw[D_+d];
    s = blockReduceSum256(s);
    if (tid==0) wk_aw[k] = s;
    return;
  }
  {
    float s0 = 0.f, s1 = 0.f;
    for (int d=tid; d<D_; d+=256){ s0 += bq[d]*aw[d]; s1 += bk[d]*aw[D_+d]; }
    s0 = blockReduceSum256(s0);
    s1 = blockReduceSum256(s1);
    if (tid==0){ qc2[0] = s0 + ab[0]; qc2[1] = s1; }
  }
}

// ht_att (bf16 in/out) + kdot[512]
__global__ __launch_bounds__(256) void k_ht2(
    const __hip_bfloat16* __restrict__ att_bf, const int* __restrict__ hts,
    const __hip_bfloat16* __restrict__ Ambf, const float* __restrict__ wk_aw,
    const float* __restrict__ qc2,
    __hip_bfloat16* __restrict__ ht_bf, float* __restrict__ kdot){
  const int b = blockIdx.x, tid = threadIdx.x;
  if (b < NP_){
    const int r = b, n = r >> 8;
    const int he = hts[r*2], te = hts[r*2+1];
    const unsigned short* ha = (const unsigned short*)att_bf + ((size_t)(n*E_+he))*H_*C_;
    const unsigned short* ta = (const unsigned short*)att_bf + ((size_t)(n*E_+te))*H_*C_;
    const int c0 = tid*4;
    float v[4] = {0.f,0.f,0.f,0.f};
    #pragma unroll
    for (int h=0;h<H_;h++){
      const ushort4v a = *(const ushort4v*)&ha[h*C_ + c0];
      const ushort4v t = *(const ushort4v*)&ta[h*C_ + c0];
      #pragma unroll
      for (int j=0;j<4;j++) v[j] = fmaf(bf2f(a[j]), bf2f(t[j]), v[j]);
    }
    float local = 0.f;
    #pragma unroll
    for (int j=0;j<4;j++){ v[j] *= (1.0f/H_); local += v[j]; }
    const float tot = blockReduceSum256(local);
    const float inv = 1.f/(tot + 1e-5f);
    ushort4v o;
    #pragma unroll
    for (int j=0;j<4;j++) o[j] = f2bfu(v[j]*inv);
    *(ushort4v*)&ht_bf[(size_t)r*C_ + c0] = o;
  } else {
    const int g = b - NP_;           // 0..511
    const unsigned short* Am = (const unsigned short*)Ambf + (size_t)g*D_;
    float s = 0.f;
    for (int d=tid; d<D_; d+=256) s += bf2f(Am[d])*wk_aw[d];
    s = blockReduceSum256(s);
    if (tid==0) kdot[g] = s + qc2[1];
  }
}

// fused GEMM1 (BK=128, reg prefetch): [0,96): KK = Am@WkT + bk ; [96,288): rs_bf = ht@seqT
__global__ __launch_bounds__(256) void k_gemm1(
    const __hip_bfloat16* __restrict__ Ambf, const __hip_bfloat16* __restrict__ WkT,
    const float* __restrict__ bk, float* __restrict__ KK,
    const __hip_bfloat16* __restrict__ ht_bf, const __hip_bfloat16* __restrict__ seqT,
    __hip_bfloat16* __restrict__ rs_bf){
  __shared__ short As[64][136];
  __shared__ short Bs[64][136];
  const int tid = threadIdx.x;
  const int w = tid>>6, l = tid&63, wm = w>>1, wn = w&1;
  const int srow = tid>>4, sk8 = (tid&15)*8;
  const short *Ap, *Bp;
  int lda, ldb, K, bm, bn;
  bool isKK;
  if (blockIdx.x < 96){
    isKK = true;
    bm = (blockIdx.x/12)*64; bn = (blockIdx.x%12)*64;
    Ap = (const short*)Ambf + (size_t)bm*D_; lda = D_; K = D_;
    Bp = (const short*)WkT + (size_t)bn*D_;  ldb = D_;
  } else {
    isKK = false;
    const int z = blockIdx.x - 96;
    const int n = z/48, rem = z%48, bmI = rem/12, bnI = rem%12;
    bm = n*P_ + bmI*64; bn = bnI*64;
    Ap = (const short*)ht_bf + (size_t)bm*C_;            lda = C_;     K = C_;
    Bp = (const short*)seqT + (size_t)bn*(N_*C_) + n*C_; ldb = N_*C_;
  }
  short8 pA[4], pB[4];
  auto loadAB = [&](int k0){
    #pragma unroll
    for (int t=0;t<4;t++){
      const int row = srow + t*16;
      pA[t] = *(const short8*)&Ap[(size_t)row*lda + k0 + sk8];
      pB[t] = *(const short8*)&Bp[(size_t)row*ldb + k0 + sk8];
    }
  };
  loadAB(0);
  f32x4 acc[2][2] = {};
  for (int k0=0;k0<K;k0+=128){
    #pragma unroll
    for (int t=0;t<4;t++){
      *(short8*)&As[srow+t*16][sk8] = pA[t];
      *(short8*)&Bs[srow+t*16][sk8] = pB[t];
    }
    __syncthreads();
    if (k0+128 < K) loadAB(k0+128);
    #pragma unroll
    for (int h=0;h<4;h++){
      short8 af[2], bfv[2];
      #pragma unroll
      for (int f=0;f<2;f++){
        af[f]  = *(short8*)&As[wm*32+f*16+(l&15)][h*32+(l>>4)*8];
        bfv[f] = *(short8*)&Bs[wn*32+f*16+(l&15)][h*32+(l>>4)*8];
      }
      #pragma unroll
      for (int i=0;i<2;i++)
        #pragma unroll
        for (int j=0;j<2;j++)
          acc[i][j] = __builtin_amdgcn_mfma_f32_16x16x32_bf16(af[i], bfv[j], acc[i][j], 0,0,0);
    }
    __syncthreads();
  }
  #pragma unroll
  for (int i=0;i<2;i++)
    #pragma unroll
    for (int j=0;j<2;j++)
      #pragma unroll
      for (int r_=0;r_<4;r_++){
        const int row = bm + wm*32 + i*16 + (l>>4)*4 + r_;
        const int col = bn + wn*32 + j*16 + (l&15);
        const float v = acc[i][j][r_];
        if (isKK) KK[(size_t)row*D_ + col] = v + bk[col];
        else      rs_bf[(size_t)row*D_ + col] = __float2bfloat16(v);
      }
}

// qdot + softmax (precomputed kdot) + blend
__global__ __launch_bounds__(256) void k_mention(
    const __hip_bfloat16* __restrict__ rs_bf, const float* __restrict__ KK,
    const float* __restrict__ vq, const float* __restrict__ qc2,
    const float* __restrict__ kdot, const int* __restrict__ pos,
    const int* __restrict__ hts,
    __hip_bfloat16* __restrict__ hess, __hip_bfloat16* __restrict__ tess){
  const int r = blockIdx.x, n = r>>8, tid = threadIdx.x;
  const unsigned short* rsp = (const unsigned short*)rs_bf + (size_t)r*D_;
  float s = 0.f;
  for (int d=tid; d<D_; d+=256) s += bf2f(rsp[d])*vq[d];
  const float q = blockReduceSum256(s) + qc2[0];
  #pragma unroll
  for (int side=0;side<2;side++){
    const int e = hts[r*2+side];
    const int base = (n*E_+e)*M_;
    float sc[4];
    #pragma unroll
    for (int m=0;m<4;m++){
      float t = q + kdot[base+m];
      t = (t > 0.f) ? t : 0.01f*t;
      sc[m] = (pos[base+m] != 0) ? t : -1e9f;
    }
    const float mx = fmaxf(fmaxf(sc[0],sc[1]), fmaxf(sc[2],sc[3]));
    float ex[4]; float sum = 0.f;
    #pragma unroll
    for (int m=0;m<4;m++){ ex[m] = expf(sc[m]-mx); sum += ex[m]; }
    const float inv = 1.f/sum;
    const float p0=ex[0]*inv, p1=ex[1]*inv, p2=ex[2]*inv, p3=ex[3]*inv;
    const float* K0 = KK + (size_t)(base+0)*D_;
    const float* K1 = KK + (size_t)(base+1)*D_;
    const float* K2 = KK + (size_t)(base+2)*D_;
    const float* K3 = KK + (size_t)(base+3)*D_;
    __hip_bfloat16* outp = (side ? tess : hess) + (size_t)r*D_;
    for (int d=tid; d<D_; d+=256)
      outp[d] = __float2bfloat16(p0*K0[d] + p1*K1[d] + p2*K2[d] + p3*K3[d]);
  }
}

// z GEMM, BK=128, reg prefetch, gather-fused A
__global__ __launch_bounds__(256) void k_gemm_z(
    const __hip_bfloat16* __restrict__ rs_bf, const __hip_bfloat16* __restrict__ ent_bf,
    const __hip_bfloat16* __restrict__ hess_bf, const __hip_bfloat16* __restrict__ tess_bf,
    const int* __restrict__ hts,
    const __hip_bfloat16* __restrict__ WhT, const __hip_bfloat16* __restrict__ WtT,
    const float* __restrict__ bh, const float* __restrict__ bt,
    float* __restrict__ zh, float* __restrict__ zt){
  const int side = blockIdx.z;
  const int bm = blockIdx.y*64, bn = blockIdx.x*64;
  const short* BT = (const short*)(side ? WtT : WhT);
  const float* bias = side ? bt : bh;
  float* Cm = side ? zt : zh;
  const short* hx  = (const short*)(side ? tess_bf : hess_bf);
  const short* rsp = (const short*)rs_bf;
  const short* enp = (const short*)ent_bf;
  __shared__ short As[64][136];
  __shared__ short Bs[64][136];
  __shared__ int e_s[64];
  const int tid = threadIdx.x;
  if (tid < 64) e_s[tid] = hts[(bm+tid)*2 + side];
  __syncthreads();
  const int w = tid>>6, l = tid&63, wm = w>>1, wn = w&1;
  const int srow = tid>>4, sk8 = (tid&15)*8;
  short8 pA[4], pB[4];
  auto loadAB = [&](int k0){
    #pragma unroll
    for (int t=0;t<4;t++){
      const int row = srow + t*16;
      const int arow = bm + row;
      const int gk = k0 + sk8;
      const short* src;
      if (gk < D_)        src = &rsp[(size_t)arow*D_ + gk];
      else if (gk < 2*D_) src = &enp[((size_t)(arow>>8)*E_ + e_s[row])*D_ + gk - D_];
      else                src = &hx[(size_t)arow*D_ + gk - 2*D_];
      pA[t] = *(const short8*)src;
      pB[t] = *(const short8*)&BT[(size_t)(bn+row)*K3D_ + gk];
    }
  };
  loadAB(0);
  f32x4 acc[2][2] = {};
  for (int k0=0;k0<K3D_;k0+=128){
    #pragma unroll
    for (int t=0;t<4;t++){
      *(short8*)&As[srow+t*16][sk8] = pA[t];
      *(short8*)&Bs[srow+t*16][sk8] = pB[t];
    }
    __syncthreads();
    if (k0+128 < K3D_) loadAB(k0+128);
    #pragma unroll
    for (int h=0;h<4;h++){
      short8 af[2], bfv[2];
      #pragma unroll
      for (int f=0;f<2;f++){
        af[f]  = *(short8*)&As[wm*32+f*16+(l&15)][h*32+(l>>4)*8];
        bfv[f] = *(short8*)&Bs[wn*32+f*16+(l&15)][h*32+(l>>4)*8];
      }
      #pragma unroll
      for (int i=0;i<2;i++)
        #pragma unroll
        for (int j=0;j<2;j++)
          acc[i][j] = __builtin_amdgcn_mfma_f32_16x16x32_bf16(af[i], bfv[j], acc[i][j], 0,0,0);
    }
    __syncthreads();
  }
  #pragma unroll
  for (int i=0;i<2;i++)
    #pragma unroll
    for (int j=0;j<2;j++)
      #pragma unroll
      for (int r_=0;r_<4;r_++){
        const int row = bm + wm*32 + i*16 + (l>>4)*4 + r_;
        const int col = bn + wn*32 + j*16 + (l&15);
        float v = acc[i][j][r_] + bias[col];
        v = tanhf(v);
        if (side==0) v = tanhf(v);
        Cm[(size_t)row*D_ + col] = v;
      }
}

// bilinear MFMA: bf16 partial out
__global__ __launch_bounds__(256) void k_bilinear(
    const float* __restrict__ zh, const float* __restrict__ zt,
    const __hip_bfloat16* __restrict__ WbT, __hip_bfloat16* __restrict__ partial){
  const int kc = blockIdx.x;          // 0..23
  const int blkI = kc >> 1, half = kc & 1;
  const int r0 = blockIdx.y*64;
  __shared__ float zh_s[64][36];
  __shared__ float zt_s[64][68];
  __shared__ short Bs[4][NLP_][40];
  const int tid = threadIdx.x;
  for (int idx=tid; idx<64*32; idx+=256){
    const int row = idx>>5, c = idx&31;
    zh_s[row][c] = zh[(size_t)(r0+row)*D_ + blkI*64 + half*32 + c];
  }
  for (int idx=tid; idx<64*64; idx+=256){
    const int row = idx>>6, c = idx&63;
    zt_s[row][c] = zt[(size_t)(r0+row)*D_ + blkI*64 + c];
  }
  const int w = tid>>6, l = tid&63;
  const int arow = w*16 + (l&15);
  const short* WT = (const short*)WbT;
  const size_t kbase = (size_t)blkI*4096 + half*2048;
  int sl[7], cl[7], k8l[7];
  #pragma unroll
  for (int t=0;t<7;t++){
    const int ci = tid + t*256;
    sl[t] = ci/448;
    const int rem = ci - sl[t]*448;
    cl[t] = rem>>2; k8l[t] = (rem&3)*8;
  }
  short8 pre[7];
  #pragma unroll
  for (int t=0;t<7;t++)
    pre[t] = *(const short8*)&WT[(size_t)cl[t]*KBL_ + kbase + (size_t)sl[t]*32 + k8l[t]];
  f32x4 acc[7] = {};
  for (int g=0; g<16; ++g){
    __syncthreads();
    #pragma unroll
    for (int t=0;t<7;t++) *(short8*)&Bs[sl[t]][cl[t]][k8l[t]] = pre[t];
    __syncthreads();
    if (g < 15){
      #pragma unroll
      for (int t=0;t<7;t++)
        pre[t] = *(const short8*)&WT[(size_t)cl[t]*KBL_ + kbase + (size_t)((g+1)*4+sl[t])*32 + k8l[t]];
    }
    #pragma unroll
    for (int ss=0;ss<4;ss++){
      const int s = g*4 + ss;
      const int iLoc = s>>1;
      const int jj = (s&1)*32 + (l>>4)*8;
      const float a = zh_s[arow][iLoc];
      f32x4 z0 = *(f32x4*)&zt_s[arow][jj];
      f32x4 z1 = *(f32x4*)&zt_s[arow][jj+4];
      short8 afr;
      #pragma unroll
      for (int t=0;t<4;t++) afr[t]   = f2bf(a*z0[t]);
      #pragma unroll
      for (int t=0;t<4;t++) afr[4+t] = f2bf(a*z1[t]);
      #pragma unroll
      for (int nf=0;nf<7;nf++){
        const short8 bfr = *(short8*)&Bs[ss][nf*16 + (l&15)][(l>>4)*8];
        acc[nf] = __builtin_amdgcn_mfma_f32_16x16x32_bf16(afr, bfr, acc[nf], 0,0,0);
      }
    }
  }
  unsigned short* pp = (unsigned short*)partial;
  #pragma unroll
  for (int nf=0;nf<7;nf++)
    #pragma unroll
    for (int r_=0;r_<4;r_++){
      const int row = r0 + w*16 + (l>>4)*4 + r_;
      const int col = nf*16 + (l&15);
      pp[((size_t)kc*NP_ + row)*NLP_ + col] = f2bfu(acc[nf][r_]);
    }
}

__global__ __launch_bounds__(256) void k_reduce(const __hip_bfloat16* __restrict__ partial,
    const float* __restrict__ bb, float* __restrict__ out){
  const int idx = blockIdx.x*256 + threadIdx.x;
  if (idx >= NP_*NL_) return;
  const int r = idx / NL_;
  const int l = idx - r*NL_;
  const unsigned short* pp = (const unsigned short*)partial;
  float s = bb[l];
  #pragma unroll
  for (int kc=0;kc<24;kc++) s += bf2f(pp[((size_t)kc*NP_ + r)*NLP_ + l]);
  out[idx] = s;
}

extern "C" void kernel_launch(void* const* d_in, const int* in_sizes, int n_in,
                              void* d_out, int out_size, void* d_ws, size_t ws_size,
                              hipStream_t stream){
  const float* seq  = (const float*)d_in[0];
  const float* attn = (const float*)d_in[1];
  const int*   pos  = (const int*)d_in[2];
  const int*   hts  = (const int*)d_in[3];
  const float* Wq = (const float*)d_in[4];
  const float* bq = (const float*)d_in[5];
  const float* Wk = (const float*)d_in[6];
  const float* bk = (const float*)d_in[7];
  const float* aw = (const float*)d_in[8];
  const float* ab = (const float*)d_in[9];
  const float* Wh = (const float*)d_in[10];
  const float* bh = (const float*)d_in[11];
  const float* Wt = (const float*)d_in[12];
  const float* bt = (const float*)d_in[13];
  const float* Wb = (const float*)d_in[14];
  const float* bb = (const float*)d_in[15];
  float* out = (float*)d_out;

  char* base = (char*)d_ws;
  size_t off = 0;
  auto alloc = [&](size_t bytes)->void*{
    void* p = base + off;
    off += (bytes + 255) & ~(size_t)255;
    return p;
  };
  __hip_bfloat16* WhT   = (__hip_bfloat16*)alloc((size_t)D_*K3D_*2);
  __hip_bfloat16* WtT   = (__hip_bfloat16*)alloc((size_t)D_*K3D_*2);
  __hip_bfloat16* WkT   = (__hip_bfloat16*)alloc((size_t)D_*D_*2);
  __hip_bfloat16* WbT   = (__hip_bfloat16*)alloc((size_t)NLP_*KBL_*2);
  __hip_bfloat16* seqT  = (__hip_bfloat16*)alloc((size_t)D_*N_*C_*2);
  __hip_bfloat16* ent_bf= (__hip_bfloat16*)alloc((size_t)N_*E_*D_*2);
  __hip_bfloat16* att_bf= (__hip_bfloat16*)alloc((size_t)N_*E_*H_*C_*2);
  __hip_bfloat16* ht_bf = (__hip_bfloat16*)alloc((size_t)NP_*C_*2);
  __hip_bfloat16* Ambf  = (__hip_bfloat16*)alloc((size_t)N_*E_*M_*D_*2);
  float* KK             = (float*)alloc((size_t)N_*E_*M_*D_*4);
  float* vq             = (float*)alloc(D_*4);
  float* wk_aw          = (float*)alloc(D_*4);
  float* qc2            = (float*)alloc(256);
  float* kdot           = (float*)alloc(512*4);
  __hip_bfloat16* rs_bf = (__hip_bfloat16*)alloc((size_t)NP_*D_*2);
  __hip_bfloat16* hess  = (__hip_bfloat16*)alloc((size_t)NP_*D_*2);
  __hip_bfloat16* tess  = (__hip_bfloat16*)alloc((size_t)NP_*D_*2);
  float* zh             = (float*)alloc((size_t)NP_*D_*4);
  float* zt             = (float*)alloc((size_t)NP_*D_*4);
  __hip_bfloat16* partial = (__hip_bfloat16*)alloc((size_t)24*NP_*NLP_*2);
  (void)ws_size; (void)in_sizes; (void)n_in; (void)out_size;

  k_prep<<<G_PREP, 256, 0, stream>>>(seq, attn, pos, Wq, bq, Wk, bk, aw, ab, Wh, Wt, Wb,
                                     WhT, WtT, WkT, WbT, seqT, ent_bf, Ambf, att_bf,
                                     vq, wk_aw, qc2);
  k_ht2<<<NP_ + 512, 256, 0, stream>>>(att_bf, hts, Ambf, wk_aw, qc2, ht_bf, kdot);
  k_gemm1<<<288, 256, 0, stream>>>(Ambf, WkT, bk, KK, ht_bf, seqT, rs_bf);
  k_mention<<<NP_, 256, 0, stream>>>(rs_bf, KK, vq, qc2, kdot, pos, hts, hess, tess);
  k_gemm_z<<<dim3(D_/64, NP_/64, 2), 256, 0, stream>>>(rs_bf, ent_bf, hess, tess, hts,
                                                       WhT, WtT, bh, bt, zh, zt);
  k_bilinear<<<dim3(24, NP_/64), 256, 0, stream>>>(zh, zt, WbT, partial);
  k_reduce<<<(NP_*NL_+255)/256, 256, 0, stream>>>(partial, bb, out);
}